// Round 3
// baseline (1158.622 us; speedup 1.0000x reference)
//
#include <hip/hip_runtime.h>
#include <hip/hip_fp16.h>
#include <math.h>

constexpr int NNODES  = 102400;
constexpr int NEDGES  = 409600;
constexpr int NGRAPHS = 2048;
constexpr int HIDDEN  = 128;

typedef __attribute__((ext_vector_type(8))) _Float16 f16x8;
typedef __attribute__((ext_vector_type(4))) float f32x4;

__device__ __forceinline__ float relu_f(float v) { return fmaxf(v, 0.0f); }

// exact 2-way f16 split with scaled lo plane: x ~= hi + lo * 2^-11
__device__ __forceinline__ void split2h(float x, _Float16& h, _Float16& l) {
  h = (_Float16)x;
  float r = x - (float)h;
  l = (_Float16)(r * 2048.0f);
}

__device__ __forceinline__ void gload_lds16(const float* g, float* l) {
  __builtin_amdgcn_global_load_lds(
      (const __attribute__((address_space(1))) void*)g,
      (__attribute__((address_space(3))) void*)l, 16, 0, 0);
}

// ---------------- prep: histograms + weight-split (merged) ----------------
__global__ void prep_kernel(const int* __restrict__ ei, const int* __restrict__ batch,
                            int* __restrict__ counts, int* __restrict__ gcounts,
                            const float* __restrict__ W10, const float* __restrict__ W20,
                            const float* __restrict__ W11, const float* __restrict__ W21,
                            const float* __restrict__ W12, const float* __restrict__ W22,
                            short* __restrict__ ws) {
  int b = blockIdx.x;
  if (b < NEDGES / 256) {
    atomicAdd(&counts[ei[NEDGES + b * 256 + threadIdx.x]], 1);
    return;
  }
  if (b < NEDGES / 256 + NNODES / 256) {
    atomicAdd(&gcounts[batch[(b - NEDGES / 256) * 256 + threadIdx.x]], 1);
    return;
  }
  int bw = b - (NEDGES / 256 + NNODES / 256);
  int n = threadIdx.x;
  if (n >= 128) return;
  const float* src; long base; int k, realK, KP;
  if (bw < 96) {
    src = W10; base = 0; k = bw; realK = 78; KP = 96;
  } else {
    int q = bw - 96;
    int mat = q >> 7;
    k = q & 127; realK = 128; KP = 128;
    const float* srcs[5] = {W20, W11, W21, W12, W22};
    const long bases[5] = {24576, 57344, 90112, 122880, 155648};
    src = srcs[mat]; base = bases[mat];
  }
  float x = (k < realK) ? src[k * 128 + n] : 0.0f;
  _Float16 h, l;
  split2h(x, h, l);
  long e = base + ((long)(k >> 5) * 128 + n) * 32 + (k & 31);
  long ps = (long)KP * 128;
  ws[e] = __builtin_bit_cast(short, h);
  ws[e + ps] = __builtin_bit_cast(short, l);
}

// ---------------- merged scans ----------------
__device__ __forceinline__ void scan_block_body(const int* in, int n, int* out_excl,
                                                int* bsums, int lb) {
  __shared__ int s[256];
  int t = threadIdx.x;
  int i = lb * 256 + t;
  int v = (i < n) ? in[i] : 0;
  s[t] = v;
  __syncthreads();
  for (int off = 1; off < 256; off <<= 1) {
    int x = (t >= off) ? s[t - off] : 0;
    __syncthreads();
    s[t] += x;
    __syncthreads();
  }
  if (i < n) out_excl[i] = s[t] - v;
  if (t == 255) bsums[lb] = s[255];
}

__global__ void scan_block2_kernel(const int* __restrict__ counts, int* __restrict__ row_ptr,
                                   int* __restrict__ bsumsA, const int* __restrict__ gcounts,
                                   int* __restrict__ gptr, int* __restrict__ bsumsB) {
  int b = blockIdx.x;
  if (b < NNODES / 256) scan_block_body(counts, NNODES, row_ptr, bsumsA, b);
  else scan_block_body(gcounts, NGRAPHS, gptr, bsumsB, b - NNODES / 256);
}

__global__ void scan_top2_kernel(int* __restrict__ bsumsA, int* __restrict__ bsumsB) {
  __shared__ int s[1024];
  int* bs = (blockIdx.x == 0) ? bsumsA : bsumsB;
  int nb  = (blockIdx.x == 0) ? (NNODES / 256) : (NGRAPHS / 256);
  int t = threadIdx.x;
  int v = (t < nb) ? bs[t] : 0;
  s[t] = v;
  __syncthreads();
  for (int off = 1; off < 1024; off <<= 1) {
    int x = (t >= off) ? s[t - off] : 0;
    __syncthreads();
    s[t] += x;
    __syncthreads();
  }
  if (t < nb) bs[t] = s[t] - v;
  if (t == 1023) bs[nb] = s[1023];
}

__global__ void scan_add2_kernel(int* __restrict__ row_ptr, const int* __restrict__ bsumsA,
                                 int* __restrict__ nxt, int* __restrict__ gptr,
                                 const int* __restrict__ bsumsB) {
  int b = blockIdx.x, t = threadIdx.x;
  if (b < NNODES / 256) {
    int i = b * 256 + t;
    int v = row_ptr[i] + bsumsA[b];
    row_ptr[i] = v;
    nxt[i] = v;
    if (i == 0) row_ptr[NNODES] = bsumsA[NNODES / 256];
  } else {
    int lb = b - NNODES / 256;
    int i = lb * 256 + t;
    gptr[i] += bsumsB[lb];
    if (i == 0) gptr[NGRAPHS] = bsumsB[NGRAPHS / 256];
  }
}

// pack: src | (dst & 31) << 27
__global__ void scatter_kernel(const int* __restrict__ ei, int* __restrict__ nxt,
                               int* __restrict__ csr_pk) {
  int e = blockIdx.x * blockDim.x + threadIdx.x;
  if (e < NEDGES) {
    int s = ei[e];
    int d = ei[NEDGES + e];
    int pos = atomicAdd(&nxt[d], 1);
    csr_pk[pos] = s | ((d & 31) << 27);
  }
}

// ---------------- GIN block body ----------------
// Gather v3: global_load_lds direct-to-LDS edge staging. Chunks of EPC edges,
// double-buffered (2 slots). Per wave: 2 load instrs per chunk -> counted
// s_waitcnt vmcnt(2) steady state (never 0 mid-loop), raw s_barrier.
// No destination VGPRs => compiler CANNOT collapse the pipeline.
// Reduce pass: ds_read_b128 staging + BN/ReLU + ds_add_f32 into tile.
// MFMA mm1/mm2 via f16x2 split (hi + 2^-11*lo).
constexpr int STRK = 132;
constexpr int CSRMAX = 384;

template<int GSTR, int SSTR, int EPC, int EPI, int KP1, bool XF>
__device__ __forceinline__ void gin_block(
    int bid, const float* __restrict__ X,
    const int* __restrict__ row_ptr, const int* __restrict__ csr,
    const short* __restrict__ w1s, const float* __restrict__ b1,
    const short* __restrict__ w2s, const float* __restrict__ b2,
    const float* __restrict__ psum, const float* __restrict__ psq,
    const float* __restrict__ bg, const float* __restrict__ bb2,
    float* __restrict__ O, float* __restrict__ bn_sum, float* __restrict__ bn_sq,
    float* buf) {
  const int t = threadIdx.x;
  const int wv = t >> 6, lane = t & 63;
  const int base = bid * 32;
  __shared__ __align__(16) float stage[4096];
  __shared__ int csr_lds[CSRMAX];
  __shared__ float scs[128], shs[128];

  if (XF) {
    if (t < 128) {
      const float mu = psum[t] * (1.0f / NNODES);
      const float va = fmaxf(psq[t] * (1.0f / NNODES) - mu * mu, 0.0f);
      const float s = bg[t] / sqrtf(va + 1e-5f);
      scs[t] = s;
      shs[t] = bb2[t] - mu * s;
    }
    __syncthreads();
  }

  // ---- self-term init of LDS tile (coalesced)
  if (GSTR == 128) {
    for (int i = t; i < 1024; i += 256) {
      const int m = i >> 5, c = (i & 31) << 2;
      float4 s = *(const float4*)&X[(long)(base + m) * 128 + c];
      if (XF) {
        s.x = relu_f(fmaf(s.x, scs[c],     shs[c]));
        s.y = relu_f(fmaf(s.y, scs[c + 1], shs[c + 1]));
        s.z = relu_f(fmaf(s.z, scs[c + 2], shs[c + 2]));
        s.w = relu_f(fmaf(s.w, scs[c + 3], shs[c + 3]));
      }
      *(float4*)&buf[m * STRK + c] = s;
    }
  } else {
    for (int i = t; i < 1536; i += 256) {
      const int m = i / 48, c = (i % 48) << 1;
      float2 v = make_float2(0.f, 0.f);
      if (c < 78) v = *(const float2*)&X[(long)(base + m) * 78 + c];
      *(float2*)&buf[m * STRK + c] = v;
    }
  }

  // ---- edge setup
  const int E0 = row_ptr[base];
  const int L  = row_ptr[base + 32] - E0;
  const int nch = (L + EPC - 1) / EPC;
  const int clampE = min(L - 1, CSRMAX - 1);
  for (int i = t; i < L && i < CSRMAX; i += 256) csr_lds[i] = csr[E0 + i];

  int sub_ld, col_ld;
  if (EPI == 2) { sub_ld = lane >> 5; col_ld = lane & 31; }
  else          { sub_ld = lane / 20; col_ld = lane - sub_ld * 20; }

  __syncthreads();  // tile init + csr_lds visible; all prior vmem drained

  float4 rsc, rsh;
  if (XF) {
    rsc = *(const float4*)&scs[col_ld << 2];
    rsh = *(const float4*)&shs[col_ld << 2];
  }

  auto gissue = [&](int c) {
    const int sb = (c & 1) * EPC * SSTR;
#pragma unroll
    for (int i = 0; i < 2; ++i) {
      const int fe = (wv * 2 + i) * EPI;
      const int e = min(c * EPC + fe + sub_ld, clampE);
      const int src = csr_lds[e] & 0x07FFFFFF;
      const float* gp = X + (size_t)src * GSTR + (col_ld << 2);
      float* lp = &stage[sb + fe * SSTR];
      if (EPI == 2 || lane < 60) gload_lds16(gp, lp);
    }
  };

  auto greduce = [&](int c) {
    const int sb = (c & 1) * EPC * SSTR;
#pragma unroll
    for (int r = 0; r < 2; ++r) {
      int es; bool ok = true;
      if (EPI == 2) es = ((((wv << 1) | (lane >> 5)) << 1) + r);
      else { es = wv * 6 + r * 3 + sub_ld; ok = (lane < 60); }
      const int eg = c * EPC + es;
      if (ok && eg < L) {
        const unsigned d = ((unsigned)csr_lds[eg]) >> 27;
        const float4 v = *(const float4*)&stage[sb + es * SSTR + (col_ld << 2)];
        float vx = v.x, vy = v.y, vz = v.z, vw = v.w;
        if (XF) {
          vx = relu_f(fmaf(vx, rsc.x, rsh.x));
          vy = relu_f(fmaf(vy, rsc.y, rsh.y));
          vz = relu_f(fmaf(vz, rsc.z, rsh.z));
          vw = relu_f(fmaf(vw, rsc.w, rsh.w));
        }
        float* pb = &buf[d * STRK + (col_ld << 2)];
        atomicAdd(pb, vx);     atomicAdd(pb + 1, vy);
        atomicAdd(pb + 2, vz); atomicAdd(pb + 3, vw);
      }
    }
  };

  if (nch > 0) { gissue(0); gissue(1); }
  for (int c = 0; c < nch; ++c) {
    if (c + 1 < nch) { asm volatile("s_waitcnt vmcnt(2)" ::: "memory"); }
    else             { asm volatile("s_waitcnt vmcnt(0)" ::: "memory"); }
    __builtin_amdgcn_sched_barrier(0);
    __builtin_amdgcn_s_barrier();
    greduce(c);
    asm volatile("s_waitcnt lgkmcnt(0)" ::: "memory");
    __builtin_amdgcn_sched_barrier(0);
    __builtin_amdgcn_s_barrier();
    if (c + 2 < nch) gissue(c + 2);
  }
  __syncthreads();

  const int rb = wv & 1, nbase = (wv >> 1) * 64;
  const int l15 = lane & 15, quad = lane >> 4;
  const int aoff = (rb * 16 + l15) * STRK;
  constexpr int PS1 = KP1 * 128;
  constexpr int PS2 = 128 * 128;
  constexpr float INVL = 1.0f / 2048.0f;

  // ---- mm1 (MFMA f16x2)
  f32x4 am1[4] = {}, ac1[4] = {};
  for (int ks = 0; ks < KP1 / 32; ++ks) {
    const int k0 = ks * 32;
    const float4 xa = *(const float4*)&buf[aoff + k0 + quad * 8];
    const float4 xb = *(const float4*)&buf[aoff + k0 + quad * 8 + 4];
    f16x8 Ah, Al;
    {
      const float xv[8] = {xa.x, xa.y, xa.z, xa.w, xb.x, xb.y, xb.z, xb.w};
#pragma unroll
      for (int j = 0; j < 8; ++j) {
        _Float16 h, l;
        split2h(xv[j], h, l);
        Ah[j] = h; Al[j] = l;
      }
    }
    f16x8 Bh[4], Bl[4];
#pragma unroll
    for (int ct = 0; ct < 4; ++ct) {
      const int n = nbase + ct * 16 + l15;
      const short* wp = w1s + ((long)(ks * 128 + n) << 5) + (quad << 3);
      Bh[ct] = *(const f16x8*)(wp);
      Bl[ct] = *(const f16x8*)(wp + PS1);
    }
#pragma unroll
    for (int ct = 0; ct < 4; ++ct) ac1[ct] = __builtin_amdgcn_mfma_f32_16x16x32_f16(Ah, Bl[ct], ac1[ct], 0, 0, 0);
#pragma unroll
    for (int ct = 0; ct < 4; ++ct) ac1[ct] = __builtin_amdgcn_mfma_f32_16x16x32_f16(Al, Bh[ct], ac1[ct], 0, 0, 0);
#pragma unroll
    for (int ct = 0; ct < 4; ++ct) am1[ct] = __builtin_amdgcn_mfma_f32_16x16x32_f16(Ah, Bh[ct], am1[ct], 0, 0, 0);
  }
  __syncthreads();

  // mid = relu(am + ac/2048 + b1)
#pragma unroll
  for (int ct = 0; ct < 4; ++ct) {
    const int n = nbase + ct * 16 + l15;
    const float bb = b1[n];
#pragma unroll
    for (int reg = 0; reg < 4; ++reg) {
      const int m = rb * 16 + quad * 4 + reg;
      buf[m * STRK + n] = relu_f(fmaf(ac1[ct][reg], INVL, am1[ct][reg]) + bb);
    }
  }
  __syncthreads();

  // ---- mm2 (MFMA f16x2)
  f32x4 am2[4] = {}, ac2[4] = {};
  for (int ks = 0; ks < 4; ++ks) {
    const int k0 = ks * 32;
    const float4 xa = *(const float4*)&buf[aoff + k0 + quad * 8];
    const float4 xb = *(const float4*)&buf[aoff + k0 + quad * 8 + 4];
    f16x8 Ah, Al;
    {
      const float xv[8] = {xa.x, xa.y, xa.z, xa.w, xb.x, xb.y, xb.z, xb.w};
#pragma unroll
      for (int j = 0; j < 8; ++j) {
        _Float16 h, l;
        split2h(xv[j], h, l);
        Ah[j] = h; Al[j] = l;
      }
    }
    f16x8 Bh[4], Bl[4];
#pragma unroll
    for (int ct = 0; ct < 4; ++ct) {
      const int n = nbase + ct * 16 + l15;
      const short* wp = w2s + ((long)(ks * 128 + n) << 5) + (quad << 3);
      Bh[ct] = *(const f16x8*)(wp);
      Bl[ct] = *(const f16x8*)(wp + PS2);
    }
#pragma unroll
    for (int ct = 0; ct < 4; ++ct) ac2[ct] = __builtin_amdgcn_mfma_f32_16x16x32_f16(Ah, Bl[ct], ac2[ct], 0, 0, 0);
#pragma unroll
    for (int ct = 0; ct < 4; ++ct) ac2[ct] = __builtin_amdgcn_mfma_f32_16x16x32_f16(Al, Bh[ct], ac2[ct], 0, 0, 0);
#pragma unroll
    for (int ct = 0; ct < 4; ++ct) am2[ct] = __builtin_amdgcn_mfma_f32_16x16x32_f16(Ah, Bh[ct], am2[ct], 0, 0, 0);
  }

  // epilogue
  float cs[4], cq[4];
#pragma unroll
  for (int ct = 0; ct < 4; ++ct) {
    const int n = nbase + ct * 16 + l15;
    const float bb = b2[n];
    float s = 0.f, q = 0.f;
#pragma unroll
    for (int reg = 0; reg < 4; ++reg) {
      const int m = rb * 16 + quad * 4 + reg;
      const float o = fmaf(ac2[ct][reg], INVL, am2[ct][reg]) + bb;
      O[(long)(base + m) * HIDDEN + n] = o;
      s += o;
      q = fmaf(o, o, q);
    }
    cs[ct] = s; cq[ct] = q;
  }
  __syncthreads();
  const int g = rb * 4 + quad;
#pragma unroll
  for (int ct = 0; ct < 4; ++ct) {
    const int n = nbase + ct * 16 + l15;
    buf[n * 8 + g] = cs[ct];
    buf[1024 + n * 8 + g] = cq[ct];
  }
  __syncthreads();
  if (t < HIDDEN) {
    float s = 0.f, q = 0.f;
    for (int gg = 0; gg < 8; ++gg) { s += buf[t * 8 + gg]; q += buf[1024 + t * 8 + gg]; }
    atomicAdd(&bn_sum[t], s);
    atomicAdd(&bn_sq[t], q);
  }
}

// ---------------- a2h split-K block (partials, no atomics) ----------------
constexpr int A2H_K = 3000, A2H_SPLIT = 200, A2H_NSPLIT = 15;
__device__ __forceinline__ void a2h_block(int rb, int sp, const float* __restrict__ A,
    const float* __restrict__ W, const float* __restrict__ bias, float* __restrict__ XAp,
    float* xT) {
  constexpr int STR = 18;
  const int t = threadIdx.x;
  const int row0 = rb * 16;
  const int k0 = sp * A2H_SPLIT;
  for (int i = t; i < 16 * 50; i += 256) {
    const int r = i / 50, kq = i - r * 50;
    const float4 v = *(const float4*)&A[(long)(row0 + r) * A2H_K + k0 + kq * 4];
    xT[(kq * 4 + 0) * STR + r] = v.x;
    xT[(kq * 4 + 1) * STR + r] = v.y;
    xT[(kq * 4 + 2) * STR + r] = v.z;
    xT[(kq * 4 + 3) * STR + r] = v.w;
  }
  __syncthreads();
  const int rg = t >> 5, cg = t & 31;
  const int r0 = rg * 2, j0 = cg * 4;
  float acc[2][4];
  for (int r = 0; r < 2; ++r)
    for (int c = 0; c < 4; ++c) acc[r][c] = 0.f;
  const float* Wp = W + (long)k0 * HIDDEN + j0;
  for (int k = 0; k < A2H_SPLIT; ++k) {
    const float4 w = *(const float4*)&Wp[(long)k * HIDDEN];
    const float2 x = *(const float2*)&xT[k * STR + r0];
    const float wa[4] = {w.x, w.y, w.z, w.w};
    for (int c = 0; c < 4; ++c) {
      acc[0][c] = fmaf(x.x, wa[c], acc[0][c]);
      acc[1][c] = fmaf(x.y, wa[c], acc[1][c]);
    }
  }
  if (sp == 0)
    for (int c = 0; c < 4; ++c) { acc[0][c] += bias[j0 + c]; acc[1][c] += bias[j0 + c]; }
  for (int r = 0; r < 2; ++r)
    for (int c = 0; c < 4; ++c)
      XAp[((size_t)sp * NGRAPHS + row0 + r0 + r) * HIDDEN + j0 + c] = acc[r][c];
}

// ---------------- conv block ----------------
__device__ __forceinline__ void conv_block(int g, const float* __restrict__ PS,
    const float* __restrict__ CK, const float* __restrict__ CB, float* __restrict__ XP,
    float* seq) {
  const int t = threadIdx.x;
  for (int i = t; i < 1000; i += 256) seq[i] = PS[g * 1000 + i];
  __syncthreads();
  const int pl = t & 31, cgp = t >> 5;
  float kr[4][8];
  for (int cc = 0; cc < 4; ++cc)
    for (int k = 0; k < 8; ++k) kr[cc][k] = CK[(cgp * 4 + cc) * 8 + k];
  float m[4] = {-1e30f, -1e30f, -1e30f, -1e30f};
  for (int i = 0; i < 32; ++i) {
    int p = pl + 32 * i;
    if (p < 993) {
      float sv[8];
      for (int k = 0; k < 8; ++k) sv[k] = seq[p + k];
      for (int cc = 0; cc < 4; ++cc) {
        float s = 0.f;
        for (int k = 0; k < 8; ++k) s = fmaf(sv[k], kr[cc][k], s);
        m[cc] = fmaxf(m[cc], s);
      }
    }
  }
  for (int off = 16; off >= 1; off >>= 1)
    for (int cc = 0; cc < 4; ++cc) m[cc] = fmaxf(m[cc], __shfl_xor(m[cc], off));
  if (pl == 0)
    for (int cc = 0; cc < 4; ++cc)
      XP[g * 32 + cgp * 4 + cc] = relu_f(m[cc] + CB[cgp * 4 + cc]);
}

// ---------------- fat0: gin0 + a2h + conv ----------------
__global__ __launch_bounds__(256, 4) void fat0_kernel(
    const float* __restrict__ x_lig, const int* __restrict__ row_ptr,
    const int* __restrict__ csr,
    const short* __restrict__ ws, const float* __restrict__ b1,
    const float* __restrict__ b2,
    float* __restrict__ O0, float* __restrict__ bn_sum, float* __restrict__ bn_sq,
    const float* __restrict__ a2h, const float* __restrict__ a1W,
    const float* __restrict__ a1b, float* __restrict__ XAp,
    const float* __restrict__ pseq, const float* __restrict__ convk,
    const float* __restrict__ convb, float* __restrict__ XP32) {
  __shared__ __align__(16) float buf[32 * STRK];
  const int b = blockIdx.x;
  if (b < NNODES / 32) {
    gin_block<78, 80, 24, 3, 96, false>(b, x_lig, row_ptr, csr, ws, b1, ws + 24576, b2,
                             nullptr, nullptr, nullptr, nullptr, O0, bn_sum, bn_sq, buf);
  } else if (b < NNODES / 32 + (NGRAPHS / 16) * A2H_NSPLIT) {
    const int q = b - NNODES / 32;
    a2h_block(q & 127, q >> 7, a2h, a1W, a1b, XAp, buf);
  } else {
    conv_block(b - (NNODES / 32 + (NGRAPHS / 16) * A2H_NSPLIT), pseq, convk, convb, XP32, buf);
  }
}

// ---------------- gin wrapper (layers 1,2) ----------------
__global__ __launch_bounds__(256, 4) void gin_kernel(
    const float* __restrict__ X, const int* __restrict__ row_ptr,
    const int* __restrict__ csr,
    const short* __restrict__ w1s, const float* __restrict__ b1,
    const short* __restrict__ w2s, const float* __restrict__ b2,
    const float* __restrict__ psum, const float* __restrict__ psq,
    const float* __restrict__ bg, const float* __restrict__ bb2,
    float* __restrict__ O, float* __restrict__ bn_sum, float* __restrict__ bn_sq) {
  __shared__ __align__(16) float buf[32 * STRK];
  gin_block<128, 128, 16, 2, 128, true>(blockIdx.x, X, row_ptr, csr, w1s, b1, w2s, b2,
                            psum, psq, bg, bb2, O, bn_sum, bn_sq, buf);
}

// ---------------- mega-head ----------------
__global__ __launch_bounds__(256) void head_kernel(
    const float* __restrict__ O, const int* __restrict__ gp,
    const float* __restrict__ psum, const float* __restrict__ psq,
    const float* __restrict__ bg, const float* __restrict__ bb2,
    const float* __restrict__ XP32, const float* __restrict__ XAp,
    const float* __restrict__ ligW, const float* __restrict__ ligb,
    const float* __restrict__ protW, const float* __restrict__ protb,
    const float* __restrict__ a2W, const float* __restrict__ a2b,
    const float* __restrict__ c1W, const float* __restrict__ c1b,
    const float* __restrict__ c2W, const float* __restrict__ c2b,
    const float* __restrict__ oW, const float* __restrict__ ob,
    float* __restrict__ out) {
  __shared__ float Ps[4][128];
  __shared__ float XAs[4][128];
  __shared__ float XPs[4][32];
  __shared__ float XCs[4][384];
  __shared__ float XC2s[4][256];
  __shared__ float XC3s[4][128];
  const int t = threadIdx.x;
  const int g0 = blockIdx.x * 4;

  // phase A: pool (inline BN of layer 2) + stage XA(sum partials, relu) / XP
  {
    const int sub = t >> 6, lane = t & 63;
    const int g = g0 + sub;
    const int f0 = lane, f1 = lane + 64;
    float mu0 = psum[f0] * (1.0f / NNODES);
    float va0 = fmaxf(psq[f0] * (1.0f / NNODES) - mu0 * mu0, 0.0f);
    float sc0 = bg[f0] / sqrtf(va0 + 1e-5f);
    float sh0 = bb2[f0] - mu0 * sc0;
    float mu1 = psum[f1] * (1.0f / NNODES);
    float va1 = fmaxf(psq[f1] * (1.0f / NNODES) - mu1 * mu1, 0.0f);
    float sc1 = bg[f1] / sqrtf(va1 + 1e-5f);
    float sh1 = bb2[f1] - mu1 * sc1;
    const int n0 = gp[g], n1 = gp[g + 1];
    float a0 = 0.f, a1 = 0.f;
    for (int n = n0; n < n1; ++n) {
      a0 += relu_f(fmaf(O[(long)n * HIDDEN + f0], sc0, sh0));
      a1 += relu_f(fmaf(O[(long)n * HIDDEN + f1], sc1, sh1));
    }
    Ps[sub][f0] = a0;
    Ps[sub][f1] = a1;
    for (int i = t; i < 512; i += 256) {
      float a = 0.f;
      for (int sp = 0; sp < A2H_NSPLIT; ++sp)
        a += XAp[(size_t)sp * NGRAPHS * HIDDEN + g0 * 128 + i];
      XAs[i >> 7][i & 127] = relu_f(a);
    }
    for (int i = t; i < 128; i += 256) XPs[i >> 5][i & 31] = XP32[g0 * 32 + i];
  }
  __syncthreads();

  // phase B: lig / prot / a2 -> XCs
  {
    const int j = t & 127, pr = t >> 7;
    const int s0 = pr * 2, s1 = pr * 2 + 1;
    float L0 = ligb[j], L1 = L0;
    float A0 = a2b[j], A1 = A0;
    for (int k = 0; k < 128; ++k) {
      const float wl = ligW[k * 128 + j];
      const float wa = a2W[k * 128 + j];
      L0 = fmaf(Ps[s0][k], wl, L0); L1 = fmaf(Ps[s1][k], wl, L1);
      A0 = fmaf(XAs[s0][k], wa, A0); A1 = fmaf(XAs[s1][k], wa, A1);
    }
    float P0 = protb[j], P1 = P0;
    for (int k = 0; k < 32; ++k) {
      const float wp = protW[k * 128 + j];
      P0 = fmaf(XPs[s0][k], wp, P0); P1 = fmaf(XPs[s1][k], wp, P1);
    }
    XCs[s0][j] = relu_f(L0);        XCs[s1][j] = relu_f(L1);
    XCs[s0][128 + j] = relu_f(P0);  XCs[s1][128 + j] = relu_f(P1);
    XCs[s0][256 + j] = relu_f(A0);  XCs[s1][256 + j] = relu_f(A1);
  }
  __syncthreads();

  // phase C: c1 (384 -> 256)
  {
    const int j = t;
    float a[4];
    const float bv = c1b[j];
    for (int s = 0; s < 4; ++s) a[s] = bv;
    for (int k = 0; k < 384; ++k) {
      const float w = c1W[k * 256 + j];
      for (int s = 0; s < 4; ++s) a[s] = fmaf(XCs[s][k], w, a[s]);
    }
    for (int s = 0; s < 4; ++s) XC2s[s][j] = relu_f(a[s]);
  }
  __syncthreads();

  // phase D: c2 (256 -> 128)
  {
    const int j = t & 127, pr = t >> 7;
    const int s0 = pr * 2, s1 = pr * 2 + 1;
    float a0 = c2b[j], a1 = a0;
    for (int k = 0; k < 256; ++k) {
      const float w = c2W[k * 128 + j];
      a0 = fmaf(XC2s[s0][k], w, a0);
      a1 = fmaf(XC2s[s1][k], w, a1);
    }
    XC3s[s0][j] = relu_f(a0);
    XC3s[s1][j] = relu_f(a1);
  }
  __syncthreads();

  // phase E: out (128 -> 1)
  {
    const int w = t >> 6, lane = t & 63;
    float p = XC3s[w][lane] * oW[lane] + XC3s[w][lane + 64] * oW[lane + 64];
    for (int off = 32; off >= 1; off >>= 1) p += __shfl_down(p, off);
    if (lane == 0) out[g0 + w] = p + ob[0];
  }
}

extern "C" void kernel_launch(void* const* d_in, const int* in_sizes, int n_in,
                              void* d_out, int out_size, void* d_ws, size_t ws_size,
                              hipStream_t stream) {
  const float* x_lig = (const float*)d_in[0];
  const float* pseq  = (const float*)d_in[1];
  const float* a2h   = (const float*)d_in[2];
  const int*   ei    = (const int*)d_in[3];
  const int*   batch = (const int*)d_in[4];
  const float* ginW1[3] = {(const float*)d_in[5],  (const float*)d_in[11], (const float*)d_in[17]};
  const float* ginb1[3] = {(const float*)d_in[6],  (const float*)d_in[12], (const float*)d_in[18]};
  const float* ginW2[3] = {(const float*)d_in[7],  (const float*)d_in[13], (const float*)d_in[19]};
  const float* ginb2[3] = {(const float*)d_in[8],  (const float*)d_in[14], (const float*)d_in[20]};
  const float* bng[3]   = {(const float*)d_in[9],  (const float*)d_in[15], (const float*)d_in[21]};
  const float* bnb[3]   = {(const float*)d_in[10], (const float*)d_in[16], (const float*)d_in[22]};
  const float* ligW  = (const float*)d_in[23]; const float* ligb  = (const float*)d_in[24];
  const float* convk = (const float*)d_in[25]; const float* convb = (const float*)d_in[26];
  const float* protW = (const float*)d_in[27]; const float* protb = (const float*)d_in[28];
  const float* a1W   = (const float*)d_in[29]; const float* a1b   = (const float*)d_in[30];
  const float* a2W   = (const float*)d_in[31]; const float* a2b   = (const float*)d_in[32];
  const float* c1W   = (const float*)d_in[33]; const float* c1b   = (const float*)d_in[34];
  const float* c2W   = (const float*)d_in[35]; const float* c2b   = (const float*)d_in[36];
  const float* oW    = (const float*)d_in[37]; const float* ob    = (const float*)d_in[38];

  char* base = (char*)d_ws;
  size_t off = 0;
  auto alloc = [&](size_t bytes) -> char* {
    char* p = base + off;
    off = (off + bytes + 511) & ~size_t(511);
    return p;
  };
  int*   counts  = (int*)alloc(NNODES * 4);
  int*   gcounts = (int*)alloc(NGRAPHS * 4);
  float* bn_sum  = (float*)alloc(3 * 128 * 4);
  float* bn_sq   = (float*)alloc(3 * 128 * 4);
  const size_t zero_bytes = off;
  float* XAp     = (float*)alloc((size_t)A2H_NSPLIT * NGRAPHS * HIDDEN * 4);
  short* wsplit   = (short*)alloc(188416 * 2);
  int*   row_ptr  = (int*)alloc((NNODES + 1) * 4);
  int*   nxt      = (int*)alloc(NNODES * 4);
  int*   gptr     = (int*)alloc((NGRAPHS + 1) * 4);
  int*   bsumsA   = (int*)alloc(401 * 4);
  int*   bsumsB   = (int*)alloc(9 * 4);
  int*   csr_pk   = (int*)alloc((size_t)NEDGES * 4);
  float* XP32     = (float*)alloc(NGRAPHS * 32 * 4);
  float* O0       = (float*)alloc((size_t)NNODES * 128 * 4);
  float* O1       = (float*)alloc((size_t)NNODES * 128 * 4);
  (void)ws_size; (void)in_sizes; (void)n_in; (void)out_size;

  hipMemsetAsync(d_ws, 0, zero_bytes, stream);

  prep_kernel<<<NEDGES / 256 + NNODES / 256 + 736, 256, 0, stream>>>(
      ei, batch, counts, gcounts, ginW1[0], ginW2[0], ginW1[1], ginW2[1],
      ginW1[2], ginW2[2], wsplit);
  scan_block2_kernel<<<NNODES / 256 + NGRAPHS / 256, 256, 0, stream>>>(
      counts, row_ptr, bsumsA, gcounts, gptr, bsumsB);
  scan_top2_kernel<<<2, 1024, 0, stream>>>(bsumsA, bsumsB);
  scan_add2_kernel<<<NNODES / 256 + NGRAPHS / 256, 256, 0, stream>>>(
      row_ptr, bsumsA, nxt, gptr, bsumsB);
  scatter_kernel<<<(NEDGES + 255) / 256, 256, 0, stream>>>(ei, nxt, csr_pk);

  fat0_kernel<<<NNODES / 32 + (NGRAPHS / 16) * A2H_NSPLIT + NGRAPHS, 256, 0, stream>>>(
      x_lig, row_ptr, csr_pk, wsplit, ginb1[0], ginb2[0],
      O0, bn_sum, bn_sq, a2h, a1W, a1b, XAp, pseq, convk, convb, XP32);

  gin_kernel<<<NNODES / 32, 256, 0, stream>>>(O0, row_ptr, csr_pk,
      wsplit + 57344, ginb1[1], wsplit + 90112, ginb2[1],
      bn_sum, bn_sq, bng[0], bnb[0], O1, bn_sum + 128, bn_sq + 128);
  gin_kernel<<<NNODES / 32, 256, 0, stream>>>(O1, row_ptr, csr_pk,
      wsplit + 122880, ginb1[2], wsplit + 155648, ginb2[2],
      bn_sum + 128, bn_sq + 128, bng[1], bnb[1], O0, bn_sum + 256, bn_sq + 256);

  head_kernel<<<NGRAPHS / 4, 256, 0, stream>>>(O0, gptr,
      bn_sum + 256, bn_sq + 256, bng[2], bnb[2], XP32, XAp,
      ligW, ligb, protW, protb, a2W, a2b, c1W, c1b, c2W, c2b, oW, ob, (float*)d_out);
}

// Round 4
// 1136.101 us; speedup vs baseline: 1.0198x; 1.0198x over previous
//
#include <hip/hip_runtime.h>
#include <hip/hip_fp16.h>
#include <math.h>

constexpr int NNODES  = 102400;
constexpr int NEDGES  = 409600;
constexpr int NGRAPHS = 2048;
constexpr int HIDDEN  = 128;

typedef __attribute__((ext_vector_type(8))) _Float16 f16x8;
typedef __attribute__((ext_vector_type(4))) float f32x4;
typedef __attribute__((ext_vector_type(4))) unsigned short us4;
typedef __attribute__((ext_vector_type(8))) unsigned short us8;

__device__ __forceinline__ float relu_f(float v) { return fmaxf(v, 0.0f); }

__device__ __forceinline__ float h2f(unsigned short s) {
  return (float)__builtin_bit_cast(_Float16, s);
}
__device__ __forceinline__ unsigned short f2h(float x) {
  return __builtin_bit_cast(unsigned short, (_Float16)x);
}

// exact 2-way f16 split with scaled lo plane: x ~= hi + lo * 2^-11
__device__ __forceinline__ void split2h(float x, _Float16& h, _Float16& l) {
  h = (_Float16)x;
  float r = x - (float)h;
  l = (_Float16)(r * 2048.0f);
}

// ---------------- prep: histograms + weight-split + x_lig->f16 ----------------
__global__ void prep_kernel(const int* __restrict__ ei, const int* __restrict__ batch,
                            int* __restrict__ counts, int* __restrict__ gcounts,
                            const float* __restrict__ W10, const float* __restrict__ W20,
                            const float* __restrict__ W11, const float* __restrict__ W21,
                            const float* __restrict__ W12, const float* __restrict__ W22,
                            short* __restrict__ ws,
                            const float* __restrict__ xlig, unsigned short* __restrict__ Ylig) {
  int b = blockIdx.x;
  if (b < NEDGES / 256) {
    atomicAdd(&counts[ei[NEDGES + b * 256 + threadIdx.x]], 1);
    return;
  }
  if (b < NEDGES / 256 + NNODES / 256) {
    atomicAdd(&gcounts[batch[(b - NEDGES / 256) * 256 + threadIdx.x]], 1);
    return;
  }
  if (b < NEDGES / 256 + NNODES / 256 + 736) {
    int bw = b - (NEDGES / 256 + NNODES / 256);
    int n = threadIdx.x;
    if (n >= 128) return;
    const float* src; long base; int k, realK, KP;
    if (bw < 96) {
      src = W10; base = 0; k = bw; realK = 78; KP = 96;
    } else {
      int q = bw - 96;
      int mat = q >> 7;
      k = q & 127; realK = 128; KP = 128;
      const float* srcs[5] = {W20, W11, W21, W12, W22};
      const long bases[5] = {24576, 57344, 90112, 122880, 155648};
      src = srcs[mat]; base = bases[mat];
    }
    float x = (k < realK) ? src[k * 128 + n] : 0.0f;
    _Float16 h, l;
    split2h(x, h, l);
    long e = base + ((long)(k >> 5) * 128 + n) * 32 + (k & 31);
    long ps = (long)KP * 128;
    ws[e] = __builtin_bit_cast(short, h);
    ws[e + ps] = __builtin_bit_cast(short, l);
    return;
  }
  // x_lig -> f16, padded 78 -> 80
  const int xi = (b - (NEDGES / 256 + NNODES / 256 + 736)) * 256 + threadIdx.x;
  const int row = xi / 20, qc = (xi - row * 20) * 4;
  if (row < NNODES) {
    us4 o;
#pragma unroll
    for (int c = 0; c < 4; ++c) {
      const int col = qc + c;
      o[c] = (col < 78) ? f2h(xlig[(size_t)row * 78 + col]) : (unsigned short)0;
    }
    *(us4*)&Ylig[(size_t)row * 80 + qc] = o;
  }
}

// ---------------- merged scans ----------------
__device__ __forceinline__ void scan_block_body(const int* in, int n, int* out_excl,
                                                int* bsums, int lb) {
  __shared__ int s[256];
  int t = threadIdx.x;
  int i = lb * 256 + t;
  int v = (i < n) ? in[i] : 0;
  s[t] = v;
  __syncthreads();
  for (int off = 1; off < 256; off <<= 1) {
    int x = (t >= off) ? s[t - off] : 0;
    __syncthreads();
    s[t] += x;
    __syncthreads();
  }
  if (i < n) out_excl[i] = s[t] - v;
  if (t == 255) bsums[lb] = s[255];
}

__global__ void scan_block2_kernel(const int* __restrict__ counts, int* __restrict__ row_ptr,
                                   int* __restrict__ bsumsA, const int* __restrict__ gcounts,
                                   int* __restrict__ gptr, int* __restrict__ bsumsB) {
  int b = blockIdx.x;
  if (b < NNODES / 256) scan_block_body(counts, NNODES, row_ptr, bsumsA, b);
  else scan_block_body(gcounts, NGRAPHS, gptr, bsumsB, b - NNODES / 256);
}

__global__ void scan_top2_kernel(int* __restrict__ bsumsA, int* __restrict__ bsumsB) {
  __shared__ int s[1024];
  int* bs = (blockIdx.x == 0) ? bsumsA : bsumsB;
  int nb  = (blockIdx.x == 0) ? (NNODES / 256) : (NGRAPHS / 256);
  int t = threadIdx.x;
  int v = (t < nb) ? bs[t] : 0;
  s[t] = v;
  __syncthreads();
  for (int off = 1; off < 1024; off <<= 1) {
    int x = (t >= off) ? s[t - off] : 0;
    __syncthreads();
    s[t] += x;
    __syncthreads();
  }
  if (t < nb) bs[t] = s[t] - v;
  if (t == 1023) bs[nb] = s[1023];
}

__global__ void scan_add2_kernel(int* __restrict__ row_ptr, const int* __restrict__ bsumsA,
                                 int* __restrict__ nxt, int* __restrict__ gptr,
                                 const int* __restrict__ bsumsB) {
  int b = blockIdx.x, t = threadIdx.x;
  if (b < NNODES / 256) {
    int i = b * 256 + t;
    int v = row_ptr[i] + bsumsA[b];
    row_ptr[i] = v;
    nxt[i] = v;
    if (i == 0) row_ptr[NNODES] = bsumsA[NNODES / 256];
  } else {
    int lb = b - NNODES / 256;
    int i = lb * 256 + t;
    gptr[i] += bsumsB[lb];
    if (i == 0) gptr[NGRAPHS] = bsumsB[NGRAPHS / 256];
  }
}

// pack: src | (dst & 31) << 27
__global__ void scatter_kernel(const int* __restrict__ ei, int* __restrict__ nxt,
                               int* __restrict__ csr_pk) {
  int e = blockIdx.x * blockDim.x + threadIdx.x;
  if (e < NEDGES) {
    int s = ei[e];
    int d = ei[NEDGES + e];
    int pos = atomicAdd(&nxt[d], 1);
    csr_pk[pos] = s | ((d & 31) << 27);
  }
}

// ---------------- bn_apply: Y = f16(relu(BN(O))) ----------------
__global__ __launch_bounds__(256) void bn_apply_kernel(
    const float* __restrict__ O, const float* __restrict__ psum,
    const float* __restrict__ psq, const float* __restrict__ g,
    const float* __restrict__ bb, unsigned short* __restrict__ Y) {
  __shared__ float scs[128], shs[128];
  const int t = threadIdx.x;
  if (t < 128) {
    const float mu = psum[t] * (1.0f / NNODES);
    const float va = fmaxf(psq[t] * (1.0f / NNODES) - mu * mu, 0.0f);
    const float s = g[t] / sqrtf(va + 1e-5f);
    scs[t] = s;
    shs[t] = bb[t] - mu * s;
  }
  __syncthreads();
  const int i = blockIdx.x * 256 + t;
  const int row = i >> 4, c8 = (i & 15) << 3;
  const float4 a = *(const float4*)&O[(size_t)row * 128 + c8];
  const float4 b = *(const float4*)&O[(size_t)row * 128 + c8 + 4];
  const float v[8] = {a.x, a.y, a.z, a.w, b.x, b.y, b.z, b.w};
  us8 o;
#pragma unroll
  for (int c = 0; c < 8; ++c)
    o[c] = f2h(relu_f(fmaf(v[c], scs[c8 + c], shs[c8 + c])));
  *(us8*)&Y[(size_t)row * 128 + c8] = o;
}

// ---------------- GIN block body ----------------
// Gather: flat segmented edge stream over f16 rows. csr staged in LDS.
// Layers 1/2: half-wave = one 256B row (32 lanes x ushort4), 4-edge unroll.
// Layer 0:    20-lane group = one 160B row, 3 edges/wave/round, 2-round unroll.
// Branchless ds_add_f32 consume into the f32 LDS tile (self-term pre-init).
// MFMA mm1/mm2 via f16x2 split (hi + 2^-11*lo).
constexpr int STRK = 132;
constexpr int CSRMAX = 512;

template<int KP1, int YSTR>
__device__ __forceinline__ void gin_block(
    int bid, const unsigned short* __restrict__ Yg,
    const int* __restrict__ row_ptr, const int* __restrict__ csr,
    const short* __restrict__ w1s, const float* __restrict__ b1,
    const short* __restrict__ w2s, const float* __restrict__ b2,
    float* __restrict__ O, float* __restrict__ bn_sum, float* __restrict__ bn_sq,
    float* buf) {
  const int t = threadIdx.x;
  const int wv = t >> 6, lane = t & 63;
  const int base = bid * 32;
  __shared__ int csr_lds[CSRMAX];

  // ---- self-term init of LDS tile (coalesced)
  constexpr int NC4 = KP1 / 4;
  for (int i = t; i < 32 * NC4; i += 256) {
    const int m = i / NC4, c4 = (i - m * NC4) << 2;
    float4 v = make_float4(0.f, 0.f, 0.f, 0.f);
    if (c4 < YSTR) {
      const us4 u = *(const us4*)&Yg[(size_t)(base + m) * YSTR + c4];
      v = make_float4(h2f(u[0]), h2f(u[1]), h2f(u[2]), h2f(u[3]));
    }
    *(float4*)&buf[m * STRK + c4] = v;
  }

  const int E0 = row_ptr[base];
  const int L  = row_ptr[base + 32] - E0;
  for (int i = t; i < L && i < CSRMAX; i += 256) csr_lds[i] = csr[E0 + i];
  __syncthreads();

  if (YSTR == 128) {
    // ---- half-wave per edge
    const int hw = t >> 5, q4 = (t & 31) << 2;
    const int js = (hw * L) >> 3, je = ((hw + 1) * L) >> 3;
    for (int jo = js; jo < je; jo += 4) {
      unsigned pk[4]; us4 u[4];
#pragma unroll
      for (int p = 0; p < 4; ++p) {
        const int e = jo + p;
        pk[p] = (e < je) ? (unsigned)((e < CSRMAX) ? csr_lds[e] : csr[E0 + e])
                         : 0xFFFFFFFFu;
        if (pk[p] != 0xFFFFFFFFu)
          u[p] = *(const us4*)&Yg[((size_t)(pk[p] & 0x07FFFFFFu)) * 128 + q4];
      }
#pragma unroll
      for (int p = 0; p < 4; ++p) {
        if (pk[p] != 0xFFFFFFFFu) {
          float* pb = &buf[(pk[p] >> 27) * STRK + q4];
          atomicAdd(pb + 0, h2f(u[p][0]));
          atomicAdd(pb + 1, h2f(u[p][1]));
          atomicAdd(pb + 2, h2f(u[p][2]));
          atomicAdd(pb + 3, h2f(u[p][3]));
        }
      }
    }
  } else {
    // ---- layer 0: 20-lane group per edge (row = 80 f16 = 160B)
    const int g3 = lane / 20;
    const int ql4 = (lane - g3 * 20) << 2;
    const bool act = (lane < 60);
    const int js = (wv * L) >> 2, je = ((wv + 1) * L) >> 2;
    for (int jo = js; jo < je; jo += 6) {
      unsigned pk[2]; us4 u[2];
#pragma unroll
      for (int p = 0; p < 2; ++p) {
        const int e = jo + p * 3 + g3;
        pk[p] = (act && e < je) ? (unsigned)((e < CSRMAX) ? csr_lds[e] : csr[E0 + e])
                                : 0xFFFFFFFFu;
        if (pk[p] != 0xFFFFFFFFu)
          u[p] = *(const us4*)&Yg[((size_t)(pk[p] & 0x07FFFFFFu)) * 80 + ql4];
      }
#pragma unroll
      for (int p = 0; p < 2; ++p) {
        if (pk[p] != 0xFFFFFFFFu) {
          float* pb = &buf[(pk[p] >> 27) * STRK + ql4];
          atomicAdd(pb + 0, h2f(u[p][0]));
          atomicAdd(pb + 1, h2f(u[p][1]));
          atomicAdd(pb + 2, h2f(u[p][2]));
          atomicAdd(pb + 3, h2f(u[p][3]));
        }
      }
    }
  }
  __syncthreads();

  const int rb = wv & 1, nbase = (wv >> 1) * 64;
  const int l15 = lane & 15, quad = lane >> 4;
  const int aoff = (rb * 16 + l15) * STRK;
  constexpr int PS1 = KP1 * 128;
  constexpr int PS2 = 128 * 128;
  constexpr float INVL = 1.0f / 2048.0f;

  // ---- mm1 (MFMA f16x2)
  f32x4 am1[4] = {}, ac1[4] = {};
  for (int ks = 0; ks < KP1 / 32; ++ks) {
    const int k0 = ks * 32;
    const float4 xa = *(const float4*)&buf[aoff + k0 + quad * 8];
    const float4 xb = *(const float4*)&buf[aoff + k0 + quad * 8 + 4];
    f16x8 Ah, Al;
    {
      const float xv[8] = {xa.x, xa.y, xa.z, xa.w, xb.x, xb.y, xb.z, xb.w};
#pragma unroll
      for (int j = 0; j < 8; ++j) {
        _Float16 h, l;
        split2h(xv[j], h, l);
        Ah[j] = h; Al[j] = l;
      }
    }
    f16x8 Bh[4], Bl[4];
#pragma unroll
    for (int ct = 0; ct < 4; ++ct) {
      const int n = nbase + ct * 16 + l15;
      const short* wp = w1s + ((long)(ks * 128 + n) << 5) + (quad << 3);
      Bh[ct] = *(const f16x8*)(wp);
      Bl[ct] = *(const f16x8*)(wp + PS1);
    }
#pragma unroll
    for (int ct = 0; ct < 4; ++ct) ac1[ct] = __builtin_amdgcn_mfma_f32_16x16x32_f16(Ah, Bl[ct], ac1[ct], 0, 0, 0);
#pragma unroll
    for (int ct = 0; ct < 4; ++ct) ac1[ct] = __builtin_amdgcn_mfma_f32_16x16x32_f16(Al, Bh[ct], ac1[ct], 0, 0, 0);
#pragma unroll
    for (int ct = 0; ct < 4; ++ct) am1[ct] = __builtin_amdgcn_mfma_f32_16x16x32_f16(Ah, Bh[ct], am1[ct], 0, 0, 0);
  }
  __syncthreads();

  // mid = relu(am + ac/2048 + b1)
#pragma unroll
  for (int ct = 0; ct < 4; ++ct) {
    const int n = nbase + ct * 16 + l15;
    const float bb = b1[n];
#pragma unroll
    for (int reg = 0; reg < 4; ++reg) {
      const int m = rb * 16 + quad * 4 + reg;
      buf[m * STRK + n] = relu_f(fmaf(ac1[ct][reg], INVL, am1[ct][reg]) + bb);
    }
  }
  __syncthreads();

  // ---- mm2 (MFMA f16x2)
  f32x4 am2[4] = {}, ac2[4] = {};
  for (int ks = 0; ks < 4; ++ks) {
    const int k0 = ks * 32;
    const float4 xa = *(const float4*)&buf[aoff + k0 + quad * 8];
    const float4 xb = *(const float4*)&buf[aoff + k0 + quad * 8 + 4];
    f16x8 Ah, Al;
    {
      const float xv[8] = {xa.x, xa.y, xa.z, xa.w, xb.x, xb.y, xb.z, xb.w};
#pragma unroll
      for (int j = 0; j < 8; ++j) {
        _Float16 h, l;
        split2h(xv[j], h, l);
        Ah[j] = h; Al[j] = l;
      }
    }
    f16x8 Bh[4], Bl[4];
#pragma unroll
    for (int ct = 0; ct < 4; ++ct) {
      const int n = nbase + ct * 16 + l15;
      const short* wp = w2s + ((long)(ks * 128 + n) << 5) + (quad << 3);
      Bh[ct] = *(const f16x8*)(wp);
      Bl[ct] = *(const f16x8*)(wp + PS2);
    }
#pragma unroll
    for (int ct = 0; ct < 4; ++ct) ac2[ct] = __builtin_amdgcn_mfma_f32_16x16x32_f16(Ah, Bl[ct], ac2[ct], 0, 0, 0);
#pragma unroll
    for (int ct = 0; ct < 4; ++ct) ac2[ct] = __builtin_amdgcn_mfma_f32_16x16x32_f16(Al, Bh[ct], ac2[ct], 0, 0, 0);
#pragma unroll
    for (int ct = 0; ct < 4; ++ct) am2[ct] = __builtin_amdgcn_mfma_f32_16x16x32_f16(Ah, Bh[ct], am2[ct], 0, 0, 0);
  }

  // epilogue: O (f32) + BN stats
  float cs[4], cq[4];
#pragma unroll
  for (int ct = 0; ct < 4; ++ct) {
    const int n = nbase + ct * 16 + l15;
    const float bb = b2[n];
    float s = 0.f, q = 0.f;
#pragma unroll
    for (int reg = 0; reg < 4; ++reg) {
      const int m = rb * 16 + quad * 4 + reg;
      const float o = fmaf(ac2[ct][reg], INVL, am2[ct][reg]) + bb;
      O[(long)(base + m) * HIDDEN + n] = o;
      s += o;
      q = fmaf(o, o, q);
    }
    cs[ct] = s; cq[ct] = q;
  }
  __syncthreads();
  const int g = rb * 4 + quad;
#pragma unroll
  for (int ct = 0; ct < 4; ++ct) {
    const int n = nbase + ct * 16 + l15;
    buf[n * 8 + g] = cs[ct];
    buf[1024 + n * 8 + g] = cq[ct];
  }
  __syncthreads();
  if (t < HIDDEN) {
    float s = 0.f, q = 0.f;
    for (int gg = 0; gg < 8; ++gg) { s += buf[t * 8 + gg]; q += buf[1024 + t * 8 + gg]; }
    atomicAdd(&bn_sum[t], s);
    atomicAdd(&bn_sq[t], q);
  }
}

// ---------------- a2h split-K block (partials, no atomics) ----------------
constexpr int A2H_K = 3000, A2H_SPLIT = 200, A2H_NSPLIT = 15;
__device__ __forceinline__ void a2h_block(int rb, int sp, const float* __restrict__ A,
    const float* __restrict__ W, const float* __restrict__ bias, float* __restrict__ XAp,
    float* xT) {
  constexpr int STR = 18;
  const int t = threadIdx.x;
  const int row0 = rb * 16;
  const int k0 = sp * A2H_SPLIT;
  for (int i = t; i < 16 * 50; i += 256) {
    const int r = i / 50, kq = i - r * 50;
    const float4 v = *(const float4*)&A[(long)(row0 + r) * A2H_K + k0 + kq * 4];
    xT[(kq * 4 + 0) * STR + r] = v.x;
    xT[(kq * 4 + 1) * STR + r] = v.y;
    xT[(kq * 4 + 2) * STR + r] = v.z;
    xT[(kq * 4 + 3) * STR + r] = v.w;
  }
  __syncthreads();
  const int rg = t >> 5, cg = t & 31;
  const int r0 = rg * 2, j0 = cg * 4;
  float acc[2][4];
  for (int r = 0; r < 2; ++r)
    for (int c = 0; c < 4; ++c) acc[r][c] = 0.f;
  const float* Wp = W + (long)k0 * HIDDEN + j0;
  for (int k = 0; k < A2H_SPLIT; ++k) {
    const float4 w = *(const float4*)&Wp[(long)k * HIDDEN];
    const float2 x = *(const float2*)&xT[k * STR + r0];
    const float wa[4] = {w.x, w.y, w.z, w.w};
    for (int c = 0; c < 4; ++c) {
      acc[0][c] = fmaf(x.x, wa[c], acc[0][c]);
      acc[1][c] = fmaf(x.y, wa[c], acc[1][c]);
    }
  }
  if (sp == 0)
    for (int c = 0; c < 4; ++c) { acc[0][c] += bias[j0 + c]; acc[1][c] += bias[j0 + c]; }
  for (int r = 0; r < 2; ++r)
    for (int c = 0; c < 4; ++c)
      XAp[((size_t)sp * NGRAPHS + row0 + r0 + r) * HIDDEN + j0 + c] = acc[r][c];
  __syncthreads();
}

// ---------------- conv block ----------------
__device__ __forceinline__ void conv_block(int g, const float* __restrict__ PS,
    const float* __restrict__ CK, const float* __restrict__ CB, float* __restrict__ XP,
    float* seq) {
  const int t = threadIdx.x;
  for (int i = t; i < 1000; i += 256) seq[i] = PS[g * 1000 + i];
  __syncthreads();
  const int pl = t & 31, cgp = t >> 5;
  float kr[4][8];
  for (int cc = 0; cc < 4; ++cc)
    for (int k = 0; k < 8; ++k) kr[cc][k] = CK[(cgp * 4 + cc) * 8 + k];
  float m[4] = {-1e30f, -1e30f, -1e30f, -1e30f};
  for (int i = 0; i < 32; ++i) {
    int p = pl + 32 * i;
    if (p < 993) {
      float sv[8];
      for (int k = 0; k < 8; ++k) sv[k] = seq[p + k];
      for (int cc = 0; cc < 4; ++cc) {
        float s = 0.f;
        for (int k = 0; k < 8; ++k) s = fmaf(sv[k], kr[cc][k], s);
        m[cc] = fmaxf(m[cc], s);
      }
    }
  }
  for (int off = 16; off >= 1; off >>= 1)
    for (int cc = 0; cc < 4; ++cc) m[cc] = fmaxf(m[cc], __shfl_xor(m[cc], off));
  if (pl == 0)
    for (int cc = 0; cc < 4; ++cc)
      XP[g * 32 + cgp * 4 + cc] = relu_f(m[cc] + CB[cgp * 4 + cc]);
}

// ---------------- fat0: gin0 + a2h(sp 0-4) + conv ----------------
__global__ __launch_bounds__(256, 4) void fat0_kernel(
    const unsigned short* __restrict__ Ylig, const int* __restrict__ row_ptr,
    const int* __restrict__ csr,
    const short* __restrict__ ws, const float* __restrict__ b1,
    const float* __restrict__ b2,
    float* __restrict__ O0, float* __restrict__ bn_sum, float* __restrict__ bn_sq,
    const float* __restrict__ a2h, const float* __restrict__ a1W,
    const float* __restrict__ a1b, float* __restrict__ XAp,
    const float* __restrict__ pseq, const float* __restrict__ convk,
    const float* __restrict__ convb, float* __restrict__ XP32) {
  __shared__ __align__(16) float buf[32 * STRK];
  const int b = blockIdx.x;
  if (b < NNODES / 32) {
    gin_block<96, 80>(b, Ylig, row_ptr, csr, ws, b1, ws + 24576, b2,
                      O0, bn_sum, bn_sq, buf);
  } else if (b < NNODES / 32 + (NGRAPHS / 16) * 5) {
    const int q = b - NNODES / 32;
    a2h_block(q & 127, q >> 7, a2h, a1W, a1b, XAp, buf);
  } else {
    conv_block(b - (NNODES / 32 + (NGRAPHS / 16) * 5), pseq, convk, convb, XP32, buf);
  }
}

// ---------------- gin wrapper (layers 1,2) + a2h tail ----------------
__global__ __launch_bounds__(256, 4) void gin_kernel(
    const unsigned short* __restrict__ Yg, const int* __restrict__ row_ptr,
    const int* __restrict__ csr,
    const short* __restrict__ w1s, const float* __restrict__ b1,
    const short* __restrict__ w2s, const float* __restrict__ b2,
    float* __restrict__ O, float* __restrict__ bn_sum, float* __restrict__ bn_sq,
    const float* __restrict__ a2h, const float* __restrict__ a1W,
    const float* __restrict__ a1b, float* __restrict__ XAp, int sp_base) {
  __shared__ __align__(16) float buf[32 * STRK];
  const int b = blockIdx.x;
  if (b < NNODES / 32) {
    gin_block<128, 128>(b, Yg, row_ptr, csr, w1s, b1, w2s, b2,
                        O, bn_sum, bn_sq, buf);
  } else {
    const int q = b - NNODES / 32;
    a2h_block(q & 127, sp_base + (q >> 7), a2h, a1W, a1b, XAp, buf);
  }
}

// ---------------- mega-head ----------------
__global__ __launch_bounds__(256) void head_kernel(
    const float* __restrict__ O, const int* __restrict__ gp,
    const float* __restrict__ psum, const float* __restrict__ psq,
    const float* __restrict__ bg, const float* __restrict__ bb2,
    const float* __restrict__ XP32, const float* __restrict__ XAp,
    const float* __restrict__ ligW, const float* __restrict__ ligb,
    const float* __restrict__ protW, const float* __restrict__ protb,
    const float* __restrict__ a2W, const float* __restrict__ a2b,
    const float* __restrict__ c1W, const float* __restrict__ c1b,
    const float* __restrict__ c2W, const float* __restrict__ c2b,
    const float* __restrict__ oW, const float* __restrict__ ob,
    float* __restrict__ out) {
  __shared__ float Ps[4][128];
  __shared__ float XAs[4][128];
  __shared__ float XPs[4][32];
  __shared__ float XCs[4][384];
  __shared__ float XC2s[4][256];
  __shared__ float XC3s[4][128];
  const int t = threadIdx.x;
  const int g0 = blockIdx.x * 4;

  // phase A: pool (inline BN of layer 2) + stage XA(sum partials, relu) / XP
  {
    const int sub = t >> 6, lane = t & 63;
    const int g = g0 + sub;
    const int f0 = lane, f1 = lane + 64;
    float mu0 = psum[f0] * (1.0f / NNODES);
    float va0 = fmaxf(psq[f0] * (1.0f / NNODES) - mu0 * mu0, 0.0f);
    float sc0 = bg[f0] / sqrtf(va0 + 1e-5f);
    float sh0 = bb2[f0] - mu0 * sc0;
    float mu1 = psum[f1] * (1.0f / NNODES);
    float va1 = fmaxf(psq[f1] * (1.0f / NNODES) - mu1 * mu1, 0.0f);
    float sc1 = bg[f1] / sqrtf(va1 + 1e-5f);
    float sh1 = bb2[f1] - mu1 * sc1;
    const int n0 = gp[g], n1 = gp[g + 1];
    float a0 = 0.f, a1 = 0.f;
    for (int n = n0; n < n1; ++n) {
      a0 += relu_f(fmaf(O[(long)n * HIDDEN + f0], sc0, sh0));
      a1 += relu_f(fmaf(O[(long)n * HIDDEN + f1], sc1, sh1));
    }
    Ps[sub][f0] = a0;
    Ps[sub][f1] = a1;
    for (int i = t; i < 512; i += 256) {
      float a = 0.f;
      for (int sp = 0; sp < A2H_NSPLIT; ++sp)
        a += XAp[(size_t)sp * NGRAPHS * HIDDEN + g0 * 128 + i];
      XAs[i >> 7][i & 127] = relu_f(a);
    }
    for (int i = t; i < 128; i += 256) XPs[i >> 5][i & 31] = XP32[g0 * 32 + i];
  }
  __syncthreads();

  // phase B: lig / prot / a2 -> XCs
  {
    const int j = t & 127, pr = t >> 7;
    const int s0 = pr * 2, s1 = pr * 2 + 1;
    float L0 = ligb[j], L1 = L0;
    float A0 = a2b[j], A1 = A0;
    for (int k = 0; k < 128; ++k) {
      const float wl = ligW[k * 128 + j];
      const float wa = a2W[k * 128 + j];
      L0 = fmaf(Ps[s0][k], wl, L0); L1 = fmaf(Ps[s1][k], wl, L1);
      A0 = fmaf(XAs[s0][k], wa, A0); A1 = fmaf(XAs[s1][k], wa, A1);
    }
    float P0 = protb[j], P1 = P0;
    for (int k = 0; k < 32; ++k) {
      const float wp = protW[k * 128 + j];
      P0 = fmaf(XPs[s0][k], wp, P0); P1 = fmaf(XPs[s1][k], wp, P1);
    }
    XCs[s0][j] = relu_f(L0);        XCs[s1][j] = relu_f(L1);
    XCs[s0][128 + j] = relu_f(P0);  XCs[s1][128 + j] = relu_f(P1);
    XCs[s0][256 + j] = relu_f(A0);  XCs[s1][256 + j] = relu_f(A1);
  }
  __syncthreads();

  // phase C: c1 (384 -> 256)
  {
    const int j = t;
    float a[4];
    const float bv = c1b[j];
    for (int s = 0; s < 4; ++s) a[s] = bv;
    for (int k = 0; k < 384; ++k) {
      const float w = c1W[k * 256 + j];
      for (int s = 0; s < 4; ++s) a[s] = fmaf(XCs[s][k], w, a[s]);
    }
    for (int s = 0; s < 4; ++s) XC2s[s][j] = relu_f(a[s]);
  }
  __syncthreads();

  // phase D: c2 (256 -> 128)
  {
    const int j = t & 127, pr = t >> 7;
    const int s0 = pr * 2, s1 = pr * 2 + 1;
    float a0 = c2b[j], a1 = a0;
    for (int k = 0; k < 256; ++k) {
      const float w = c2W[k * 128 + j];
      a0 = fmaf(XC2s[s0][k], w, a0);
      a1 = fmaf(XC2s[s1][k], w, a1);
    }
    XC3s[s0][j] = relu_f(a0);
    XC3s[s1][j] = relu_f(a1);
  }
  __syncthreads();

  // phase E: out (128 -> 1)
  {
    const int w = t >> 6, lane = t & 63;
    float p = XC3s[w][lane] * oW[lane] + XC3s[w][lane + 64] * oW[lane + 64];
    for (int off = 32; off >= 1; off >>= 1) p += __shfl_down(p, off);
    if (lane == 0) out[g0 + w] = p + ob[0];
  }
}

extern "C" void kernel_launch(void* const* d_in, const int* in_sizes, int n_in,
                              void* d_out, int out_size, void* d_ws, size_t ws_size,
                              hipStream_t stream) {
  const float* x_lig = (const float*)d_in[0];
  const float* pseq  = (const float*)d_in[1];
  const float* a2h   = (const float*)d_in[2];
  const int*   ei    = (const int*)d_in[3];
  const int*   batch = (const int*)d_in[4];
  const float* ginW1[3] = {(const float*)d_in[5],  (const float*)d_in[11], (const float*)d_in[17]};
  const float* ginb1[3] = {(const float*)d_in[6],  (const float*)d_in[12], (const float*)d_in[18]};
  const float* ginW2[3] = {(const float*)d_in[7],  (const float*)d_in[13], (const float*)d_in[19]};
  const float* ginb2[3] = {(const float*)d_in[8],  (const float*)d_in[14], (const float*)d_in[20]};
  const float* bng[3]   = {(const float*)d_in[9],  (const float*)d_in[15], (const float*)d_in[21]};
  const float* bnb[3]   = {(const float*)d_in[10], (const float*)d_in[16], (const float*)d_in[22]};
  const float* ligW  = (const float*)d_in[23]; const float* ligb  = (const float*)d_in[24];
  const float* convk = (const float*)d_in[25]; const float* convb = (const float*)d_in[26];
  const float* protW = (const float*)d_in[27]; const float* protb = (const float*)d_in[28];
  const float* a1W   = (const float*)d_in[29]; const float* a1b   = (const float*)d_in[30];
  const float* a2W   = (const float*)d_in[31]; const float* a2b   = (const float*)d_in[32];
  const float* c1W   = (const float*)d_in[33]; const float* c1b   = (const float*)d_in[34];
  const float* c2W   = (const float*)d_in[35]; const float* c2b   = (const float*)d_in[36];
  const float* oW    = (const float*)d_in[37]; const float* ob    = (const float*)d_in[38];

  char* base = (char*)d_ws;
  size_t off = 0;
  auto alloc = [&](size_t bytes) -> char* {
    char* p = base + off;
    off = (off + bytes + 511) & ~size_t(511);
    return p;
  };
  int*   counts  = (int*)alloc(NNODES * 4);
  int*   gcounts = (int*)alloc(NGRAPHS * 4);
  float* bn_sum  = (float*)alloc(3 * 128 * 4);
  float* bn_sq   = (float*)alloc(3 * 128 * 4);
  const size_t zero_bytes = off;
  float* XAp     = (float*)alloc((size_t)A2H_NSPLIT * NGRAPHS * HIDDEN * 4);
  short* wsplit   = (short*)alloc(188416 * 2);
  int*   row_ptr  = (int*)alloc((NNODES + 1) * 4);
  int*   nxt      = (int*)alloc(NNODES * 4);
  int*   gptr     = (int*)alloc((NGRAPHS + 1) * 4);
  int*   bsumsA   = (int*)alloc(401 * 4);
  int*   bsumsB   = (int*)alloc(9 * 4);
  int*   csr_pk   = (int*)alloc((size_t)NEDGES * 4);
  float* XP32     = (float*)alloc(NGRAPHS * 32 * 4);
  float* O0       = (float*)alloc((size_t)NNODES * 128 * 4);
  unsigned short* Ylig = (unsigned short*)alloc((size_t)NNODES * 80 * 2);
  unsigned short* Ybuf = (unsigned short*)alloc((size_t)NNODES * 128 * 2);
  (void)ws_size; (void)in_sizes; (void)n_in; (void)out_size;

  hipMemsetAsync(d_ws, 0, zero_bytes, stream);

  prep_kernel<<<NEDGES / 256 + NNODES / 256 + 736 + 8000, 256, 0, stream>>>(
      ei, batch, counts, gcounts, ginW1[0], ginW2[0], ginW1[1], ginW2[1],
      ginW1[2], ginW2[2], wsplit, x_lig, Ylig);
  scan_block2_kernel<<<NNODES / 256 + NGRAPHS / 256, 256, 0, stream>>>(
      counts, row_ptr, bsumsA, gcounts, gptr, bsumsB);
  scan_top2_kernel<<<2, 1024, 0, stream>>>(bsumsA, bsumsB);
  scan_add2_kernel<<<NNODES / 256 + NGRAPHS / 256, 256, 0, stream>>>(
      row_ptr, bsumsA, nxt, gptr, bsumsB);
  scatter_kernel<<<(NEDGES + 255) / 256, 256, 0, stream>>>(ei, nxt, csr_pk);

  // layer 0 (+ a2h sp 0-4 + conv)
  fat0_kernel<<<NNODES / 32 + (NGRAPHS / 16) * 5 + NGRAPHS, 256, 0, stream>>>(
      Ylig, row_ptr, csr_pk, wsplit, ginb1[0], ginb2[0],
      O0, bn_sum, bn_sq, a2h, a1W, a1b, XAp, pseq, convk, convb, XP32);

  bn_apply_kernel<<<NNODES * 16 / 256, 256, 0, stream>>>(
      O0, bn_sum, bn_sq, bng[0], bnb[0], Ybuf);

  // layer 1 (+ a2h sp 5-9)
  gin_kernel<<<NNODES / 32 + (NGRAPHS / 16) * 5, 256, 0, stream>>>(
      Ybuf, row_ptr, csr_pk,
      wsplit + 57344, ginb1[1], wsplit + 90112, ginb2[1],
      O0, bn_sum + 128, bn_sq + 128, a2h, a1W, a1b, XAp, 5);

  bn_apply_kernel<<<NNODES * 16 / 256, 256, 0, stream>>>(
      O0, bn_sum + 128, bn_sq + 128, bng[1], bnb[1], Ybuf);

  // layer 2 (+ a2h sp 10-14)
  gin_kernel<<<NNODES / 32 + (NGRAPHS / 16) * 5, 256, 0, stream>>>(
      Ybuf, row_ptr, csr_pk,
      wsplit + 122880, ginb1[2], wsplit + 155648, ginb2[2],
      O0, bn_sum + 256, bn_sq + 256, a2h, a1W, a1b, XAp, 10);

  head_kernel<<<NGRAPHS / 4, 256, 0, stream>>>(O0, gptr,
      bn_sum + 256, bn_sq + 256, bng[2], bnb[2], XP32, XAp,
      ligW, ligb, protW, protb, a2W, a2b, c1W, c1b, c2W, c2b, oW, ob, (float*)d_out);
}

// Round 5
// 851.399 us; speedup vs baseline: 1.3608x; 1.3344x over previous
//
#include <hip/hip_runtime.h>
#include <hip/hip_fp16.h>
#include <math.h>

constexpr int NNODES  = 102400;
constexpr int NEDGES  = 409600;
constexpr int NGRAPHS = 2048;
constexpr int HIDDEN  = 128;

typedef __attribute__((ext_vector_type(8))) _Float16 f16x8;
typedef __attribute__((ext_vector_type(4))) float f32x4;
typedef __attribute__((ext_vector_type(4))) unsigned short us4;

__device__ __forceinline__ float relu_f(float v) { return fmaxf(v, 0.0f); }
__device__ __forceinline__ float h2f(unsigned short s) {
  return (float)__builtin_bit_cast(_Float16, s);
}
__device__ __forceinline__ unsigned short f2h(float x) {
  return __builtin_bit_cast(unsigned short, (_Float16)x);
}
// exact 2-way f16 split with scaled lo plane: x ~= hi + lo * 2^-11
__device__ __forceinline__ void split2h(float x, _Float16& h, _Float16& l) {
  h = (_Float16)x;
  float r = x - (float)h;
  l = (_Float16)(r * 2048.0f);
}

// ---------------- prep: 3 histograms + weight-split ----------------
__global__ void prep_kernel(const int* __restrict__ ei, const int* __restrict__ batch,
                            int* __restrict__ counts_d, int* __restrict__ counts_s,
                            int* __restrict__ gcounts,
                            const float* __restrict__ W10, const float* __restrict__ W20,
                            const float* __restrict__ W11, const float* __restrict__ W21,
                            const float* __restrict__ W12, const float* __restrict__ W22,
                            short* __restrict__ ws) {
  int b = blockIdx.x;
  if (b < 1600) { atomicAdd(&counts_d[ei[NEDGES + b * 256 + threadIdx.x]], 1); return; }
  if (b < 3200) { atomicAdd(&counts_s[ei[(b - 1600) * 256 + threadIdx.x]], 1); return; }
  if (b < 3600) { atomicAdd(&gcounts[batch[(b - 3200) * 256 + threadIdx.x]], 1); return; }
  int bw = b - 3600;
  int n = threadIdx.x;
  if (n >= 128) return;
  const float* src; long base; int k, realK, KP;
  if (bw < 96) {
    src = W10; base = 0; k = bw; realK = 78; KP = 96;
  } else {
    int q = bw - 96;
    int mat = q >> 7;
    k = q & 127; realK = 128; KP = 128;
    const float* srcs[5] = {W20, W11, W21, W12, W22};
    const long bases[5] = {24576, 57344, 90112, 122880, 155648};
    src = srcs[mat]; base = bases[mat];
  }
  float x = (k < realK) ? src[k * 128 + n] : 0.0f;
  _Float16 h, l;
  split2h(x, h, l);
  long e = base + ((long)(k >> 5) * 128 + n) * 32 + (k & 31);
  long ps = (long)KP * 128;
  ws[e] = __builtin_bit_cast(short, h);
  ws[e + ps] = __builtin_bit_cast(short, l);
}

// ---------------- merged scans (3 arrays) ----------------
__device__ __forceinline__ void scan_block_body(const int* in, int n, int* out_excl,
                                                int* bsums, int lb) {
  __shared__ int s[256];
  int t = threadIdx.x;
  int i = lb * 256 + t;
  int v = (i < n) ? in[i] : 0;
  s[t] = v;
  __syncthreads();
  for (int off = 1; off < 256; off <<= 1) {
    int x = (t >= off) ? s[t - off] : 0;
    __syncthreads();
    s[t] += x;
    __syncthreads();
  }
  if (i < n) out_excl[i] = s[t] - v;
  if (t == 255) bsums[lb] = s[255];
}

__global__ void scan_block3_kernel(const int* __restrict__ counts_d, int* __restrict__ row_ptr,
                                   int* __restrict__ bsA,
                                   const int* __restrict__ counts_s, int* __restrict__ nxt_s,
                                   int* __restrict__ bsS,
                                   const int* __restrict__ gcounts, int* __restrict__ gptr,
                                   int* __restrict__ bsB) {
  int b = blockIdx.x;
  if (b < NNODES / 256) scan_block_body(counts_d, NNODES, row_ptr, bsA, b);
  else if (b < 2 * (NNODES / 256)) scan_block_body(counts_s, NNODES, nxt_s, bsS, b - NNODES / 256);
  else scan_block_body(gcounts, NGRAPHS, gptr, bsB, b - 2 * (NNODES / 256));
}

__global__ void scan_top3_kernel(int* __restrict__ bsA, int* __restrict__ bsS,
                                 int* __restrict__ bsB) {
  __shared__ int s[1024];
  int* bs = (blockIdx.x == 0) ? bsA : (blockIdx.x == 1) ? bsS : bsB;
  int nb  = (blockIdx.x == 2) ? (NGRAPHS / 256) : (NNODES / 256);
  int t = threadIdx.x;
  int v = (t < nb) ? bs[t] : 0;
  s[t] = v;
  __syncthreads();
  for (int off = 1; off < 1024; off <<= 1) {
    int x = (t >= off) ? s[t - off] : 0;
    __syncthreads();
    s[t] += x;
    __syncthreads();
  }
  if (t < nb) bs[t] = s[t] - v;
  if (t == 1023) bs[nb] = s[1023];
}

__global__ void scan_add3_kernel(int* __restrict__ row_ptr, const int* __restrict__ bsA,
                                 int* __restrict__ nxt_d,
                                 int* __restrict__ nxt_s, const int* __restrict__ bsS,
                                 int* __restrict__ gptr, const int* __restrict__ bsB) {
  int b = blockIdx.x, t = threadIdx.x;
  if (b < NNODES / 256) {
    int i = b * 256 + t;
    int v = row_ptr[i] + bsA[b];
    row_ptr[i] = v;
    nxt_d[i] = v;
    if (i == 0) row_ptr[NNODES] = bsA[NNODES / 256];
  } else if (b < 2 * (NNODES / 256)) {
    int lb = b - NNODES / 256;
    int i = lb * 256 + t;
    nxt_s[i] += bsS[lb];
  } else {
    int lb = b - 2 * (NNODES / 256);
    int i = lb * 256 + t;
    gptr[i] += bsB[lb];
    if (i == 0) gptr[NGRAPHS] = bsB[NGRAPHS / 256];
  }
}

// csc[pos_src] = (src, pos_dst)
__global__ void scatterAB_kernel(const int* __restrict__ ei, int* __restrict__ nxt_d,
                                 int* __restrict__ nxt_s, int2* __restrict__ csc) {
  int e = blockIdx.x * blockDim.x + threadIdx.x;
  if (e < NEDGES) {
    int s = ei[e];
    int d = ei[NEDGES + e];
    int pd = atomicAdd(&nxt_d[d], 1);
    int ps = atomicAdd(&nxt_s[s], 1);
    csc[ps] = make_int2(s, pd);
  }
}

// ---------------- conv block ----------------
__device__ __forceinline__ void conv_block(int g, const float* __restrict__ PS,
    const float* __restrict__ CK, const float* __restrict__ CB, float* __restrict__ XP,
    float* seq) {
  const int t = threadIdx.x;
  for (int i = t; i < 1000; i += 256) seq[i] = PS[g * 1000 + i];
  __syncthreads();
  const int pl = t & 31, cgp = t >> 5;
  float kr[4][8];
  for (int cc = 0; cc < 4; ++cc)
    for (int k = 0; k < 8; ++k) kr[cc][k] = CK[(cgp * 4 + cc) * 8 + k];
  float m[4] = {-1e30f, -1e30f, -1e30f, -1e30f};
  for (int i = 0; i < 32; ++i) {
    int p = pl + 32 * i;
    if (p < 993) {
      float sv[8];
      for (int k = 0; k < 8; ++k) sv[k] = seq[p + k];
      for (int cc = 0; cc < 4; ++cc) {
        float s = 0.f;
        for (int k = 0; k < 8; ++k) s = fmaf(sv[k], kr[cc][k], s);
        m[cc] = fmaxf(m[cc], s);
      }
    }
  }
  for (int off = 16; off >= 1; off >>= 1)
    for (int cc = 0; cc < 4; ++cc) m[cc] = fmaxf(m[cc], __shfl_xor(m[cc], off));
  if (pl == 0)
    for (int cc = 0; cc < 4; ++cc)
      XP[g * 32 + cgp * 4 + cc] = relu_f(m[cc] + CB[cgp * 4 + cc]);
}

// ---------------- scatter_e layer 0 (+conv): E0[pos_d] = f16(x_lig[src]) ----------------
__global__ __launch_bounds__(256) void se0_kernel(
    const float* __restrict__ xlig, const int2* __restrict__ csc,
    unsigned short* __restrict__ E,
    const float* __restrict__ pseq, const float* __restrict__ convk,
    const float* __restrict__ convb, float* __restrict__ XP32) {
  __shared__ float cbuf[1008];
  const int b = blockIdx.x;
  if (b < NEDGES / 64) {
    const int hw = threadIdx.x >> 5, l = threadIdx.x & 31, c0 = l << 2;
    for (int it = 0; it < 8; ++it) {
      const int e = b * 64 + it * 8 + hw;
      if (c0 < 80) {
        const int2 sd = csc[e];
        float2 a = make_float2(0.f, 0.f), g2 = make_float2(0.f, 0.f);
        if (c0 < 78) a = *(const float2*)&xlig[(size_t)sd.x * 78 + c0];
        if (c0 + 2 < 78) g2 = *(const float2*)&xlig[(size_t)sd.x * 78 + c0 + 2];
        us4 o = {f2h(a.x), f2h(a.y), f2h(g2.x), f2h(g2.y)};
        *(us4*)&E[(size_t)sd.y * 80 + c0] = o;
      }
    }
  } else {
    conv_block(b - NEDGES / 64, pseq, convk, convb, XP32, cbuf);
  }
}

// ---------------- scatter_e layers 1/2: E[pos_d] = f16(relu(BN(O[src]))) ----------------
__global__ __launch_bounds__(256) void se12_kernel(
    const float* __restrict__ O, const int2* __restrict__ csc,
    const float* __restrict__ psum, const float* __restrict__ psq,
    const float* __restrict__ bg, const float* __restrict__ bb,
    unsigned short* __restrict__ E) {
  __shared__ float scs[128], shs[128];
  const int t = threadIdx.x;
  if (t < 128) {
    const float mu = psum[t] * (1.0f / NNODES);
    const float va = fmaxf(psq[t] * (1.0f / NNODES) - mu * mu, 0.0f);
    const float s = bg[t] / sqrtf(va + 1e-5f);
    scs[t] = s;
    shs[t] = bb[t] - mu * s;
  }
  __syncthreads();
  const int hw = t >> 5, l = t & 31, c0 = l << 2;
  const float4 rsc = *(const float4*)&scs[c0];
  const float4 rsh = *(const float4*)&shs[c0];
  for (int it = 0; it < 8; ++it) {
    const int e = blockIdx.x * 64 + it * 8 + hw;
    const int2 sd = csc[e];
    const float4 v = *(const float4*)&O[(size_t)sd.x * 128 + c0];
    us4 o = {f2h(relu_f(fmaf(v.x, rsc.x, rsh.x))),
             f2h(relu_f(fmaf(v.y, rsc.y, rsh.y))),
             f2h(relu_f(fmaf(v.z, rsc.z, rsh.z))),
             f2h(relu_f(fmaf(v.w, rsc.w, rsh.w)))};
    *(us4*)&E[(size_t)sd.y * 128 + c0] = o;
  }
}

// ---------------- GIN block body ----------------
// Reduce: each half-wave exclusively owns 4 dst rows; reads its E-slab
// segment SEQUENTIALLY (dst-CSR order), register-accumulates (self-term
// inline), single plain LDS store per row. No LDS atomics, no guards.
// MFMA mm1/mm2 via f16x2 split (hi + 2^-11*lo).
constexpr int STRK = 132;

template<int KP1, bool L0>
__device__ __forceinline__ void gin_block(
    int bid, const float* __restrict__ X,
    const int* __restrict__ row_ptr, const unsigned short* __restrict__ E,
    const short* __restrict__ w1s, const float* __restrict__ b1,
    const short* __restrict__ w2s, const float* __restrict__ b2,
    const float* __restrict__ psum, const float* __restrict__ psq,
    const float* __restrict__ bg, const float* __restrict__ bb2,
    float* __restrict__ O, float* __restrict__ bn_sum, float* __restrict__ bn_sq,
    float* buf) {
  const int t = threadIdx.x;
  const int wv = t >> 6, lane = t & 63;
  const int base = bid * 32;
  __shared__ float scs[128], shs[128];

  if (!L0) {
    if (t < 128) {
      const float mu = psum[t] * (1.0f / NNODES);
      const float va = fmaxf(psq[t] * (1.0f / NNODES) - mu * mu, 0.0f);
      const float s = bg[t] / sqrtf(va + 1e-5f);
      scs[t] = s;
      shs[t] = bb2[t] - mu * s;
    }
    __syncthreads();
  }

  const int hw = t >> 5, c0 = (t & 31) << 2;
  constexpr int ESTR = L0 ? 80 : 128;
  float4 rsc, rsh;
  if (!L0) {
    rsc = *(const float4*)&scs[c0];
    rsh = *(const float4*)&shs[c0];
  }
#pragma unroll
  for (int i = 0; i < 4; ++i) {
    const int node = base + hw * 4 + i;
    float4 acc;
    if (L0) {
      float2 a = make_float2(0.f, 0.f), g2 = make_float2(0.f, 0.f);
      if (c0 < 78) a = *(const float2*)&X[(size_t)node * 78 + c0];
      if (c0 + 2 < 78) g2 = *(const float2*)&X[(size_t)node * 78 + c0 + 2];
      acc = make_float4(a.x, a.y, g2.x, g2.y);
    } else {
      const float4 s = *(const float4*)&X[(size_t)node * 128 + c0];
      acc.x = relu_f(fmaf(s.x, rsc.x, rsh.x));
      acc.y = relu_f(fmaf(s.y, rsc.y, rsh.y));
      acc.z = relu_f(fmaf(s.z, rsc.z, rsh.z));
      acc.w = relu_f(fmaf(s.w, rsc.w, rsh.w));
    }
    if (!L0 || c0 < 80) {
      const int es = row_ptr[node], ee = row_ptr[node + 1];
      for (int e = es; e < ee; ++e) {
        const us4 u = *(const us4*)&E[(size_t)e * ESTR + c0];
        acc.x += h2f(u[0]); acc.y += h2f(u[1]);
        acc.z += h2f(u[2]); acc.w += h2f(u[3]);
      }
    }
    if (c0 < KP1) *(float4*)&buf[(hw * 4 + i) * STRK + c0] = acc;
  }
  __syncthreads();

  const int rb = wv & 1, nbase = (wv >> 1) * 64;
  const int l15 = lane & 15, quad = lane >> 4;
  const int aoff = (rb * 16 + l15) * STRK;
  constexpr int PS1 = KP1 * 128;
  constexpr int PS2 = 128 * 128;
  constexpr float INVL = 1.0f / 2048.0f;

  // ---- mm1 (MFMA f16x2)
  f32x4 am1[4] = {}, ac1[4] = {};
  for (int ks = 0; ks < KP1 / 32; ++ks) {
    const int k0 = ks * 32;
    const float4 xa = *(const float4*)&buf[aoff + k0 + quad * 8];
    const float4 xb = *(const float4*)&buf[aoff + k0 + quad * 8 + 4];
    f16x8 Ah, Al;
    {
      const float xv[8] = {xa.x, xa.y, xa.z, xa.w, xb.x, xb.y, xb.z, xb.w};
#pragma unroll
      for (int j = 0; j < 8; ++j) {
        _Float16 h, l;
        split2h(xv[j], h, l);
        Ah[j] = h; Al[j] = l;
      }
    }
    f16x8 Bh[4], Bl[4];
#pragma unroll
    for (int ct = 0; ct < 4; ++ct) {
      const int n = nbase + ct * 16 + l15;
      const short* wp = w1s + ((long)(ks * 128 + n) << 5) + (quad << 3);
      Bh[ct] = *(const f16x8*)(wp);
      Bl[ct] = *(const f16x8*)(wp + PS1);
    }
#pragma unroll
    for (int ct = 0; ct < 4; ++ct) ac1[ct] = __builtin_amdgcn_mfma_f32_16x16x32_f16(Ah, Bl[ct], ac1[ct], 0, 0, 0);
#pragma unroll
    for (int ct = 0; ct < 4; ++ct) ac1[ct] = __builtin_amdgcn_mfma_f32_16x16x32_f16(Al, Bh[ct], ac1[ct], 0, 0, 0);
#pragma unroll
    for (int ct = 0; ct < 4; ++ct) am1[ct] = __builtin_amdgcn_mfma_f32_16x16x32_f16(Ah, Bh[ct], am1[ct], 0, 0, 0);
  }
  __syncthreads();

  // mid = relu(am + ac/2048 + b1)
#pragma unroll
  for (int ct = 0; ct < 4; ++ct) {
    const int n = nbase + ct * 16 + l15;
    const float bb = b1[n];
#pragma unroll
    for (int reg = 0; reg < 4; ++reg) {
      const int m = rb * 16 + quad * 4 + reg;
      buf[m * STRK + n] = relu_f(fmaf(ac1[ct][reg], INVL, am1[ct][reg]) + bb);
    }
  }
  __syncthreads();

  // ---- mm2 (MFMA f16x2)
  f32x4 am2[4] = {}, ac2[4] = {};
  for (int ks = 0; ks < 4; ++ks) {
    const int k0 = ks * 32;
    const float4 xa = *(const float4*)&buf[aoff + k0 + quad * 8];
    const float4 xb = *(const float4*)&buf[aoff + k0 + quad * 8 + 4];
    f16x8 Ah, Al;
    {
      const float xv[8] = {xa.x, xa.y, xa.z, xa.w, xb.x, xb.y, xb.z, xb.w};
#pragma unroll
      for (int j = 0; j < 8; ++j) {
        _Float16 h, l;
        split2h(xv[j], h, l);
        Ah[j] = h; Al[j] = l;
      }
    }
    f16x8 Bh[4], Bl[4];
#pragma unroll
    for (int ct = 0; ct < 4; ++ct) {
      const int n = nbase + ct * 16 + l15;
      const short* wp = w2s + ((long)(ks * 128 + n) << 5) + (quad << 3);
      Bh[ct] = *(const f16x8*)(wp);
      Bl[ct] = *(const f16x8*)(wp + PS2);
    }
#pragma unroll
    for (int ct = 0; ct < 4; ++ct) ac2[ct] = __builtin_amdgcn_mfma_f32_16x16x32_f16(Ah, Bl[ct], ac2[ct], 0, 0, 0);
#pragma unroll
    for (int ct = 0; ct < 4; ++ct) ac2[ct] = __builtin_amdgcn_mfma_f32_16x16x32_f16(Al, Bh[ct], ac2[ct], 0, 0, 0);
#pragma unroll
    for (int ct = 0; ct < 4; ++ct) am2[ct] = __builtin_amdgcn_mfma_f32_16x16x32_f16(Ah, Bh[ct], am2[ct], 0, 0, 0);
  }

  // epilogue: O (f32, in place) + BN stats
  float cs[4], cq[4];
#pragma unroll
  for (int ct = 0; ct < 4; ++ct) {
    const int n = nbase + ct * 16 + l15;
    const float bb = b2[n];
    float s = 0.f, q = 0.f;
#pragma unroll
    for (int reg = 0; reg < 4; ++reg) {
      const int m = rb * 16 + quad * 4 + reg;
      const float o = fmaf(ac2[ct][reg], INVL, am2[ct][reg]) + bb;
      O[(long)(base + m) * HIDDEN + n] = o;
      s += o;
      q = fmaf(o, o, q);
    }
    cs[ct] = s; cq[ct] = q;
  }
  __syncthreads();
  const int g = rb * 4 + quad;
#pragma unroll
  for (int ct = 0; ct < 4; ++ct) {
    const int n = nbase + ct * 16 + l15;
    buf[n * 8 + g] = cs[ct];
    buf[1024 + n * 8 + g] = cq[ct];
  }
  __syncthreads();
  if (t < HIDDEN) {
    float s = 0.f, q = 0.f;
    for (int gg = 0; gg < 8; ++gg) { s += buf[t * 8 + gg]; q += buf[1024 + t * 8 + gg]; }
    atomicAdd(&bn_sum[t], s);
    atomicAdd(&bn_sq[t], q);
  }
}

// ---------------- a2h split-K block (partials, no atomics) ----------------
constexpr int A2H_K = 3000, A2H_SPLIT = 200, A2H_NSPLIT = 15;
__device__ __forceinline__ void a2h_block(int rb, int sp, const float* __restrict__ A,
    const float* __restrict__ W, const float* __restrict__ bias, float* __restrict__ XAp,
    float* xT) {
  constexpr int STR = 18;
  const int t = threadIdx.x;
  const int row0 = rb * 16;
  const int k0 = sp * A2H_SPLIT;
  for (int i = t; i < 16 * 50; i += 256) {
    const int r = i / 50, kq = i - r * 50;
    const float4 v = *(const float4*)&A[(long)(row0 + r) * A2H_K + k0 + kq * 4];
    xT[(kq * 4 + 0) * STR + r] = v.x;
    xT[(kq * 4 + 1) * STR + r] = v.y;
    xT[(kq * 4 + 2) * STR + r] = v.z;
    xT[(kq * 4 + 3) * STR + r] = v.w;
  }
  __syncthreads();
  const int rg = t >> 5, cg = t & 31;
  const int r0 = rg * 2, j0 = cg * 4;
  float acc[2][4];
  for (int r = 0; r < 2; ++r)
    for (int c = 0; c < 4; ++c) acc[r][c] = 0.f;
  const float* Wp = W + (long)k0 * HIDDEN + j0;
  for (int k = 0; k < A2H_SPLIT; ++k) {
    const float4 w = *(const float4*)&Wp[(long)k * HIDDEN];
    const float2 x = *(const float2*)&xT[k * STR + r0];
    const float wa[4] = {w.x, w.y, w.z, w.w};
    for (int c = 0; c < 4; ++c) {
      acc[0][c] = fmaf(x.x, wa[c], acc[0][c]);
      acc[1][c] = fmaf(x.y, wa[c], acc[1][c]);
    }
  }
  if (sp == 0)
    for (int c = 0; c < 4; ++c) { acc[0][c] += bias[j0 + c]; acc[1][c] += bias[j0 + c]; }
  for (int r = 0; r < 2; ++r)
    for (int c = 0; c < 4; ++c)
      XAp[((size_t)sp * NGRAPHS + row0 + r0 + r) * HIDDEN + j0 + c] = acc[r][c];
  __syncthreads();
}

// ---------------- fat0: gin0-reduce + a2h(sp 0-4) ----------------
__global__ __launch_bounds__(256, 4) void fat0_kernel(
    const float* __restrict__ x_lig, const int* __restrict__ row_ptr,
    const unsigned short* __restrict__ E,
    const short* __restrict__ ws, const float* __restrict__ b1,
    const float* __restrict__ b2,
    float* __restrict__ O0, float* __restrict__ bn_sum, float* __restrict__ bn_sq,
    const float* __restrict__ a2h, const float* __restrict__ a1W,
    const float* __restrict__ a1b, float* __restrict__ XAp) {
  __shared__ __align__(16) float buf[32 * STRK];
  const int b = blockIdx.x;
  if (b < NNODES / 32) {
    gin_block<96, true>(b, x_lig, row_ptr, E, ws, b1, ws + 24576, b2,
                        nullptr, nullptr, nullptr, nullptr, O0, bn_sum, bn_sq, buf);
  } else {
    const int q = b - NNODES / 32;
    a2h_block(q & 127, q >> 7, a2h, a1W, a1b, XAp, buf);
  }
}

// ---------------- gin wrapper (layers 1,2) + a2h tail ----------------
__global__ __launch_bounds__(256, 4) void gin_kernel(
    const float* __restrict__ O, const int* __restrict__ row_ptr,
    const unsigned short* __restrict__ E,
    const short* __restrict__ w1s, const float* __restrict__ b1,
    const short* __restrict__ w2s, const float* __restrict__ b2,
    const float* __restrict__ psum, const float* __restrict__ psq,
    const float* __restrict__ bg, const float* __restrict__ bb2,
    float* __restrict__ bn_sum, float* __restrict__ bn_sq,
    const float* __restrict__ a2h, const float* __restrict__ a1W,
    const float* __restrict__ a1b, float* __restrict__ XAp, int sp_base) {
  __shared__ __align__(16) float buf[32 * STRK];
  const int b = blockIdx.x;
  if (b < NNODES / 32) {
    gin_block<128, false>(b, O, row_ptr, E, w1s, b1, w2s, b2,
                          psum, psq, bg, bb2, (float*)O, bn_sum, bn_sq, buf);
  } else {
    const int q = b - NNODES / 32;
    a2h_block(q & 127, sp_base + (q >> 7), a2h, a1W, a1b, XAp, buf);
  }
}

// ---------------- mega-head ----------------
__global__ __launch_bounds__(256) void head_kernel(
    const float* __restrict__ O, const int* __restrict__ gp,
    const float* __restrict__ psum, const float* __restrict__ psq,
    const float* __restrict__ bg, const float* __restrict__ bb2,
    const float* __restrict__ XP32, const float* __restrict__ XAp,
    const float* __restrict__ ligW, const float* __restrict__ ligb,
    const float* __restrict__ protW, const float* __restrict__ protb,
    const float* __restrict__ a2W, const float* __restrict__ a2b,
    const float* __restrict__ c1W, const float* __restrict__ c1b,
    const float* __restrict__ c2W, const float* __restrict__ c2b,
    const float* __restrict__ oW, const float* __restrict__ ob,
    float* __restrict__ out) {
  __shared__ float Ps[4][128];
  __shared__ float XAs[4][128];
  __shared__ float XPs[4][32];
  __shared__ float XCs[4][384];
  __shared__ float XC2s[4][256];
  __shared__ float XC3s[4][128];
  const int t = threadIdx.x;
  const int g0 = blockIdx.x * 4;

  // phase A: pool (inline BN of layer 2) + stage XA(sum partials, relu) / XP
  {
    const int sub = t >> 6, lane = t & 63;
    const int g = g0 + sub;
    const int f0 = lane, f1 = lane + 64;
    float mu0 = psum[f0] * (1.0f / NNODES);
    float va0 = fmaxf(psq[f0] * (1.0f / NNODES) - mu0 * mu0, 0.0f);
    float sc0 = bg[f0] / sqrtf(va0 + 1e-5f);
    float sh0 = bb2[f0] - mu0 * sc0;
    float mu1 = psum[f1] * (1.0f / NNODES);
    float va1 = fmaxf(psq[f1] * (1.0f / NNODES) - mu1 * mu1, 0.0f);
    float sc1 = bg[f1] / sqrtf(va1 + 1e-5f);
    float sh1 = bb2[f1] - mu1 * sc1;
    const int n0 = gp[g], n1 = gp[g + 1];
    float a0 = 0.f, a1 = 0.f;
    for (int n = n0; n < n1; ++n) {
      a0 += relu_f(fmaf(O[(long)n * HIDDEN + f0], sc0, sh0));
      a1 += relu_f(fmaf(O[(long)n * HIDDEN + f1], sc1, sh1));
    }
    Ps[sub][f0] = a0;
    Ps[sub][f1] = a1;
    for (int i = t; i < 512; i += 256) {
      float a = 0.f;
      for (int sp = 0; sp < A2H_NSPLIT; ++sp)
        a += XAp[(size_t)sp * NGRAPHS * HIDDEN + g0 * 128 + i];
      XAs[i >> 7][i & 127] = relu_f(a);
    }
    for (int i = t; i < 128; i += 256) XPs[i >> 5][i & 31] = XP32[g0 * 32 + i];
  }
  __syncthreads();

  // phase B: lig / prot / a2 -> XCs
  {
    const int j = t & 127, pr = t >> 7;
    const int s0 = pr * 2, s1 = pr * 2 + 1;
    float L0 = ligb[j], L1 = L0;
    float A0 = a2b[j], A1 = A0;
    for (int k = 0; k < 128; ++k) {
      const float wl = ligW[k * 128 + j];
      const float wa = a2W[k * 128 + j];
      L0 = fmaf(Ps[s0][k], wl, L0); L1 = fmaf(Ps[s1][k], wl, L1);
      A0 = fmaf(XAs[s0][k], wa, A0); A1 = fmaf(XAs[s1][k], wa, A1);
    }
    float P0 = protb[j], P1 = P0;
    for (int k = 0; k < 32; ++k) {
      const float wp = protW[k * 128 + j];
      P0 = fmaf(XPs[s0][k], wp, P0); P1 = fmaf(XPs[s1][k], wp, P1);
    }
    XCs[s0][j] = relu_f(L0);        XCs[s1][j] = relu_f(L1);
    XCs[s0][128 + j] = relu_f(P0);  XCs[s1][128 + j] = relu_f(P1);
    XCs[s0][256 + j] = relu_f(A0);  XCs[s1][256 + j] = relu_f(A1);
  }
  __syncthreads();

  // phase C: c1 (384 -> 256)
  {
    const int j = t;
    float a[4];
    const float bv = c1b[j];
    for (int s = 0; s < 4; ++s) a[s] = bv;
    for (int k = 0; k < 384; ++k) {
      const float w = c1W[k * 256 + j];
      for (int s = 0; s < 4; ++s) a[s] = fmaf(XCs[s][k], w, a[s]);
    }
    for (int s = 0; s < 4; ++s) XC2s[s][j] = relu_f(a[s]);
  }
  __syncthreads();

  // phase D: c2 (256 -> 128)
  {
    const int j = t & 127, pr = t >> 7;
    const int s0 = pr * 2, s1 = pr * 2 + 1;
    float a0 = c2b[j], a1 = a0;
    for (int k = 0; k < 256; ++k) {
      const float w = c2W[k * 128 + j];
      a0 = fmaf(XC2s[s0][k], w, a0);
      a1 = fmaf(XC2s[s1][k], w, a1);
    }
    XC3s[s0][j] = relu_f(a0);
    XC3s[s1][j] = relu_f(a1);
  }
  __syncthreads();

  // phase E: out (128 -> 1)
  {
    const int w = t >> 6, lane = t & 63;
    float p = XC3s[w][lane] * oW[lane] + XC3s[w][lane + 64] * oW[lane + 64];
    for (int off = 32; off >= 1; off >>= 1) p += __shfl_down(p, off);
    if (lane == 0) out[g0 + w] = p + ob[0];
  }
}

extern "C" void kernel_launch(void* const* d_in, const int* in_sizes, int n_in,
                              void* d_out, int out_size, void* d_ws, size_t ws_size,
                              hipStream_t stream) {
  const float* x_lig = (const float*)d_in[0];
  const float* pseq  = (const float*)d_in[1];
  const float* a2h   = (const float*)d_in[2];
  const int*   ei    = (const int*)d_in[3];
  const int*   batch = (const int*)d_in[4];
  const float* ginW1[3] = {(const float*)d_in[5],  (const float*)d_in[11], (const float*)d_in[17]};
  const float* ginb1[3] = {(const float*)d_in[6],  (const float*)d_in[12], (const float*)d_in[18]};
  const float* ginW2[3] = {(const float*)d_in[7],  (const float*)d_in[13], (const float*)d_in[19]};
  const float* ginb2[3] = {(const float*)d_in[8],  (const float*)d_in[14], (const float*)d_in[20]};
  const float* bng[3]   = {(const float*)d_in[9],  (const float*)d_in[15], (const float*)d_in[21]};
  const float* bnb[3]   = {(const float*)d_in[10], (const float*)d_in[16], (const float*)d_in[22]};
  const float* ligW  = (const float*)d_in[23]; const float* ligb  = (const float*)d_in[24];
  const float* convk = (const float*)d_in[25]; const float* convb = (const float*)d_in[26];
  const float* protW = (const float*)d_in[27]; const float* protb = (const float*)d_in[28];
  const float* a1W   = (const float*)d_in[29]; const float* a1b   = (const float*)d_in[30];
  const float* a2W   = (const float*)d_in[31]; const float* a2b   = (const float*)d_in[32];
  const float* c1W   = (const float*)d_in[33]; const float* c1b   = (const float*)d_in[34];
  const float* c2W   = (const float*)d_in[35]; const float* c2b   = (const float*)d_in[36];
  const float* oW    = (const float*)d_in[37]; const float* ob    = (const float*)d_in[38];

  char* base = (char*)d_ws;
  size_t off = 0;
  auto alloc = [&](size_t bytes) -> char* {
    char* p = base + off;
    off = (off + bytes + 511) & ~size_t(511);
    return p;
  };
  int*   counts_d = (int*)alloc(NNODES * 4);
  int*   counts_s = (int*)alloc(NNODES * 4);
  int*   gcounts  = (int*)alloc(NGRAPHS * 4);
  float* bn_sum   = (float*)alloc(3 * 128 * 4);
  float* bn_sq    = (float*)alloc(3 * 128 * 4);
  const size_t zero_bytes = off;
  float* XAp     = (float*)alloc((size_t)A2H_NSPLIT * NGRAPHS * HIDDEN * 4);
  short* wsplit   = (short*)alloc(188416 * 2);
  int*   row_ptr  = (int*)alloc((NNODES + 1) * 4);
  int*   nxt_d    = (int*)alloc(NNODES * 4);
  int*   nxt_s    = (int*)alloc(NNODES * 4);
  int*   gptr     = (int*)alloc((NGRAPHS + 1) * 4);
  int*   bsA      = (int*)alloc(401 * 4);
  int*   bsS      = (int*)alloc(401 * 4);
  int*   bsB      = (int*)alloc(9 * 4);
  int2*  csc      = (int2*)alloc((size_t)NEDGES * 8);
  float* XP32     = (float*)alloc(NGRAPHS * 32 * 4);
  float* O0       = (float*)alloc((size_t)NNODES * 128 * 4);
  unsigned short* E = (unsigned short*)alloc((size_t)NEDGES * 128 * 2);
  (void)ws_size; (void)in_sizes; (void)n_in; (void)out_size;

  hipMemsetAsync(d_ws, 0, zero_bytes, stream);

  prep_kernel<<<1600 + 1600 + 400 + 736, 256, 0, stream>>>(
      ei, batch, counts_d, counts_s, gcounts,
      ginW1[0], ginW2[0], ginW1[1], ginW2[1], ginW1[2], ginW2[2], wsplit);
  scan_block3_kernel<<<2 * (NNODES / 256) + NGRAPHS / 256, 256, 0, stream>>>(
      counts_d, row_ptr, bsA, counts_s, nxt_s, bsS, gcounts, gptr, bsB);
  scan_top3_kernel<<<3, 1024, 0, stream>>>(bsA, bsS, bsB);
  scan_add3_kernel<<<2 * (NNODES / 256) + NGRAPHS / 256, 256, 0, stream>>>(
      row_ptr, bsA, nxt_d, nxt_s, bsS, gptr, bsB);
  scatterAB_kernel<<<(NEDGES + 255) / 256, 256, 0, stream>>>(ei, nxt_d, nxt_s, csc);

  // E0 scatter (+ conv)
  se0_kernel<<<NEDGES / 64 + NGRAPHS, 256, 0, stream>>>(
      x_lig, csc, E, pseq, convk, convb, XP32);

  // layer 0 reduce+MLP (+ a2h sp 0-4)
  fat0_kernel<<<NNODES / 32 + (NGRAPHS / 16) * 5, 256, 0, stream>>>(
      x_lig, row_ptr, E, wsplit, ginb1[0], ginb2[0],
      O0, bn_sum, bn_sq, a2h, a1W, a1b, XAp);

  // layer 1
  se12_kernel<<<NEDGES / 64, 256, 0, stream>>>(
      O0, csc, bn_sum, bn_sq, bng[0], bnb[0], E);
  gin_kernel<<<NNODES / 32 + (NGRAPHS / 16) * 5, 256, 0, stream>>>(
      O0, row_ptr, E,
      wsplit + 57344, ginb1[1], wsplit + 90112, ginb2[1],
      bn_sum, bn_sq, bng[0], bnb[0],
      bn_sum + 128, bn_sq + 128, a2h, a1W, a1b, XAp, 5);

  // layer 2
  se12_kernel<<<NEDGES / 64, 256, 0, stream>>>(
      O0, csc, bn_sum + 128, bn_sq + 128, bng[1], bnb[1], E);
  gin_kernel<<<NNODES / 32 + (NGRAPHS / 16) * 5, 256, 0, stream>>>(
      O0, row_ptr, E,
      wsplit + 122880, ginb1[2], wsplit + 155648, ginb2[2],
      bn_sum + 128, bn_sq + 128, bng[1], bnb[1],
      bn_sum + 256, bn_sq + 256, a2h, a1W, a1b, XAp, 10);

  head_kernel<<<NGRAPHS / 4, 256, 0, stream>>>(O0, gptr,
      bn_sum + 256, bn_sq + 256, bng[2], bnb[2], XP32, XAp,
      ligW, ligb, protW, protb, a2W, a2b, c1W, c1b, c2W, c2b, oW, ob, (float*)d_out);
}

// Round 7
// 829.590 us; speedup vs baseline: 1.3966x; 1.0263x over previous
//
#include <hip/hip_runtime.h>
#include <hip/hip_fp16.h>
#include <math.h>

constexpr int NNODES  = 102400;
constexpr int NEDGES  = 409600;
constexpr int NGRAPHS = 2048;
constexpr int HIDDEN  = 128;

typedef __attribute__((ext_vector_type(8))) _Float16 f16x8;
typedef __attribute__((ext_vector_type(4))) float f32x4;
typedef __attribute__((ext_vector_type(4))) unsigned short us4;

__device__ __forceinline__ float relu_f(float v) { return fmaxf(v, 0.0f); }
__device__ __forceinline__ float h2f(unsigned short s) {
  return (float)__builtin_bit_cast(_Float16, s);
}
__device__ __forceinline__ unsigned short f2h(float x) {
  return __builtin_bit_cast(unsigned short, (_Float16)x);
}
// exact 2-way f16 split with scaled lo plane: x ~= hi + lo * 2^-11
__device__ __forceinline__ void split2h(float x, _Float16& h, _Float16& l) {
  h = (_Float16)x;
  float r = x - (float)h;
  l = (_Float16)(r * 2048.0f);
}

// ---------------- prep: 3 histograms + weight-split ----------------
__global__ void prep_kernel(const int* __restrict__ ei, const int* __restrict__ batch,
                            int* __restrict__ counts_d, int* __restrict__ counts_s,
                            int* __restrict__ gcounts,
                            const float* __restrict__ W10, const float* __restrict__ W20,
                            const float* __restrict__ W11, const float* __restrict__ W21,
                            const float* __restrict__ W12, const float* __restrict__ W22,
                            short* __restrict__ ws) {
  int b = blockIdx.x;
  if (b < 1600) { atomicAdd(&counts_d[ei[NEDGES + b * 256 + threadIdx.x]], 1); return; }
  if (b < 3200) { atomicAdd(&counts_s[ei[(b - 1600) * 256 + threadIdx.x]], 1); return; }
  if (b < 3600) { atomicAdd(&gcounts[batch[(b - 3200) * 256 + threadIdx.x]], 1); return; }
  int bw = b - 3600;
  int n = threadIdx.x;
  if (n >= 128) return;
  const float* src; long base; int k, realK, KP;
  if (bw < 96) {
    src = W10; base = 0; k = bw; realK = 78; KP = 96;
  } else {
    int q = bw - 96;
    int mat = q >> 7;
    k = q & 127; realK = 128; KP = 128;
    const float* srcs[5] = {W20, W11, W21, W12, W22};
    const long bases[5] = {24576, 57344, 90112, 122880, 155648};
    src = srcs[mat]; base = bases[mat];
  }
  float x = (k < realK) ? src[k * 128 + n] : 0.0f;
  _Float16 h, l;
  split2h(x, h, l);
  long e = base + ((long)(k >> 5) * 128 + n) * 32 + (k & 31);
  long ps = (long)KP * 128;
  ws[e] = __builtin_bit_cast(short, h);
  ws[e + ps] = __builtin_bit_cast(short, l);
}

// ---------------- merged scans (3 arrays) ----------------
__device__ __forceinline__ void scan_block_body(const int* in, int n, int* out_excl,
                                                int* bsums, int lb) {
  __shared__ int s[256];
  int t = threadIdx.x;
  int i = lb * 256 + t;
  int v = (i < n) ? in[i] : 0;
  s[t] = v;
  __syncthreads();
  for (int off = 1; off < 256; off <<= 1) {
    int x = (t >= off) ? s[t - off] : 0;
    __syncthreads();
    s[t] += x;
    __syncthreads();
  }
  if (i < n) out_excl[i] = s[t] - v;
  if (t == 255) bsums[lb] = s[255];
}

__global__ void scan_block3_kernel(const int* __restrict__ counts_d, int* __restrict__ row_ptr,
                                   int* __restrict__ bsA,
                                   const int* __restrict__ counts_s, int* __restrict__ nxt_s,
                                   int* __restrict__ bsS,
                                   const int* __restrict__ gcounts, int* __restrict__ gptr,
                                   int* __restrict__ bsB) {
  int b = blockIdx.x;
  if (b < NNODES / 256) scan_block_body(counts_d, NNODES, row_ptr, bsA, b);
  else if (b < 2 * (NNODES / 256)) scan_block_body(counts_s, NNODES, nxt_s, bsS, b - NNODES / 256);
  else scan_block_body(gcounts, NGRAPHS, gptr, bsB, b - 2 * (NNODES / 256));
}

__global__ void scan_top3_kernel(int* __restrict__ bsA, int* __restrict__ bsS,
                                 int* __restrict__ bsB) {
  __shared__ int s[1024];
  int* bs = (blockIdx.x == 0) ? bsA : (blockIdx.x == 1) ? bsS : bsB;
  int nb  = (blockIdx.x == 2) ? (NGRAPHS / 256) : (NNODES / 256);
  int t = threadIdx.x;
  int v = (t < nb) ? bs[t] : 0;
  s[t] = v;
  __syncthreads();
  for (int off = 1; off < 1024; off <<= 1) {
    int x = (t >= off) ? s[t - off] : 0;
    __syncthreads();
    s[t] += x;
    __syncthreads();
  }
  if (t < nb) bs[t] = s[t] - v;
  if (t == 1023) bs[nb] = s[1023];
}

__global__ void scan_add3_kernel(int* __restrict__ row_ptr, const int* __restrict__ bsA,
                                 int* __restrict__ nxt_d,
                                 int* __restrict__ nxt_s, const int* __restrict__ bsS,
                                 int* __restrict__ csp,
                                 int* __restrict__ gptr, const int* __restrict__ bsB) {
  int b = blockIdx.x, t = threadIdx.x;
  if (b < NNODES / 256) {
    int i = b * 256 + t;
    int v = row_ptr[i] + bsA[b];
    row_ptr[i] = v;
    nxt_d[i] = v;
    if (i == 0) row_ptr[NNODES] = bsA[NNODES / 256];
  } else if (b < 2 * (NNODES / 256)) {
    int lb = b - NNODES / 256;
    int i = lb * 256 + t;
    int v = nxt_s[i] + bsS[lb];
    nxt_s[i] = v;
    csp[i] = v;
    if (i == 0) csp[NNODES] = bsS[NNODES / 256];
  } else {
    int lb = b - 2 * (NNODES / 256);
    int i = lb * 256 + t;
    gptr[i] += bsB[lb];
    if (i == 0) gptr[NGRAPHS] = bsB[NGRAPHS / 256];
  }
}

// csc[pos_src] = (src, pos_dst)
__global__ void scatterAB_kernel(const int* __restrict__ ei, int* __restrict__ nxt_d,
                                 int* __restrict__ nxt_s, int2* __restrict__ csc) {
  int e = blockIdx.x * blockDim.x + threadIdx.x;
  if (e < NEDGES) {
    int s = ei[e];
    int d = ei[NEDGES + e];
    int pd = atomicAdd(&nxt_d[d], 1);
    int ps = atomicAdd(&nxt_s[s], 1);
    csc[ps] = make_int2(s, pd);
  }
}

// ---------------- conv block ----------------
__device__ __forceinline__ void conv_block(int g, const float* __restrict__ PS,
    const float* __restrict__ CK, const float* __restrict__ CB, float* __restrict__ XP,
    float* seq) {
  const int t = threadIdx.x;
  for (int i = t; i < 1000; i += 256) seq[i] = PS[g * 1000 + i];
  __syncthreads();
  const int pl = t & 31, cgp = t >> 5;
  float kr[4][8];
  for (int cc = 0; cc < 4; ++cc)
    for (int k = 0; k < 8; ++k) kr[cc][k] = CK[(cgp * 4 + cc) * 8 + k];
  float m[4] = {-1e30f, -1e30f, -1e30f, -1e30f};
  for (int i = 0; i < 32; ++i) {
    int p = pl + 32 * i;
    if (p < 993) {
      float sv[8];
      for (int k = 0; k < 8; ++k) sv[k] = seq[p + k];
      for (int cc = 0; cc < 4; ++cc) {
        float s = 0.f;
        for (int k = 0; k < 8; ++k) s = fmaf(sv[k], kr[cc][k], s);
        m[cc] = fmaxf(m[cc], s);
      }
    }
  }
  for (int off = 16; off >= 1; off >>= 1)
    for (int cc = 0; cc < 4; ++cc) m[cc] = fmaxf(m[cc], __shfl_xor(m[cc], off));
  if (pl == 0)
    for (int cc = 0; cc < 4; ++cc)
      XP[g * 32 + cgp * 4 + cc] = relu_f(m[cc] + CB[cgp * 4 + cc]);
}

// ---------------- scatter_e layer 0 (+conv): E0[pos_d] = f16(x_lig[src]) ----------------
__global__ __launch_bounds__(256) void se0_kernel(
    const float* __restrict__ xlig, const int2* __restrict__ csc,
    unsigned short* __restrict__ E,
    const float* __restrict__ pseq, const float* __restrict__ convk,
    const float* __restrict__ convb, float* __restrict__ XP32) {
  __shared__ float cbuf[1008];
  const int b = blockIdx.x;
  if (b < NEDGES / 64) {
    const int hw = threadIdx.x >> 5, l = threadIdx.x & 31, c0 = l << 2;
    for (int it = 0; it < 8; ++it) {
      const int e = b * 64 + it * 8 + hw;
      if (c0 < 80) {
        const int2 sd = csc[e];
        float2 a = make_float2(0.f, 0.f), g2 = make_float2(0.f, 0.f);
        if (c0 < 78) a = *(const float2*)&xlig[(size_t)sd.x * 78 + c0];
        if (c0 + 2 < 78) g2 = *(const float2*)&xlig[(size_t)sd.x * 78 + c0 + 2];
        us4 o = {f2h(a.x), f2h(a.y), f2h(g2.x), f2h(g2.y)};
        *(us4*)&E[(size_t)sd.y * 80 + c0] = o;
      }
    }
  } else {
    conv_block(b - NEDGES / 64, pseq, convk, convb, XP32, cbuf);
  }
}

// ---------------- GIN block body ----------------
// Reduce: half-wave owns 4 dst rows; per node a static 6-deep burst of
// sequential E-row loads (clamped addresses, masked accumulate) + rare
// serial tail. Per-edge BN+ReLU applied on CONSUME (E holds raw f16).
// O stored as raw f16 (consistent with E quantization).
// Epilogue: barrier (mm2 LDS reads done), then scatter own output rows
// (raw f16, from LDS tile) to Eout[pos_d] via the contiguous CSC slab.
// MFMA mm1/mm2 via f16x2 split (hi + 2^-11*lo).
constexpr int STRK = 132;

template<int KP1, bool L0, bool SCAT>
__device__ __forceinline__ void gin_block(
    int bid, const float* __restrict__ Xf, unsigned short* __restrict__ Oh,
    const int* __restrict__ row_ptr, const unsigned short* __restrict__ Ein,
    const int* __restrict__ csp, const int2* __restrict__ csc,
    unsigned short* __restrict__ Eout,
    const short* __restrict__ w1s, const float* __restrict__ b1,
    const short* __restrict__ w2s, const float* __restrict__ b2,
    const float* __restrict__ psum, const float* __restrict__ psq,
    const float* __restrict__ bg, const float* __restrict__ bb2,
    float* __restrict__ bn_sum, float* __restrict__ bn_sq,
    float* buf) {
  const int t = threadIdx.x;
  const int wv = t >> 6, lane = t & 63;
  const int base = bid * 32;
  __shared__ float scs[128], shs[128];

  if (!L0) {
    if (t < 128) {
      const float mu = psum[t] * (1.0f / NNODES);
      const float va = fmaxf(psq[t] * (1.0f / NNODES) - mu * mu, 0.0f);
      const float s = bg[t] / sqrtf(va + 1e-5f);
      scs[t] = s;
      shs[t] = bb2[t] - mu * s;
    }
    __syncthreads();
  }

  const int hw = t >> 5, c0 = (t & 31) << 2;
  constexpr int ESTR = L0 ? 80 : 128;
  float4 rsc, rsh;
  if (!L0) {
    rsc = *(const float4*)&scs[c0];
    rsh = *(const float4*)&shs[c0];
  }

  const int n0 = base + hw * 4;
  int rp[5];
#pragma unroll
  for (int j = 0; j < 5; ++j) rp[j] = row_ptr[n0 + j];

#pragma unroll
  for (int i = 0; i < 4; ++i) {
    const int node = n0 + i;
    float4 acc;
    if (L0) {
      float2 a = make_float2(0.f, 0.f), g2 = make_float2(0.f, 0.f);
      if (c0 < 78) a = *(const float2*)&Xf[(size_t)node * 78 + c0];
      if (c0 + 2 < 78) g2 = *(const float2*)&Xf[(size_t)node * 78 + c0 + 2];
      acc = make_float4(a.x, a.y, g2.x, g2.y);
    } else {
      const us4 u = *(const us4*)&Oh[(size_t)node * 128 + c0];
      acc.x = relu_f(fmaf(h2f(u[0]), rsc.x, rsh.x));
      acc.y = relu_f(fmaf(h2f(u[1]), rsc.y, rsh.y));
      acc.z = relu_f(fmaf(h2f(u[2]), rsc.z, rsh.z));
      acc.w = relu_f(fmaf(h2f(u[3]), rsc.w, rsh.w));
    }
    if (!L0 || c0 < 80) {
      const int es = rp[i], ee = rp[i + 1];
      auto ldE = [&](int e) -> us4 {
        return *(const us4*)&Ein[(size_t)min(e, NEDGES - 1) * ESTR + c0];
      };
      auto accum = [&](us4 u) {
        if (L0) {
          acc.x += h2f(u[0]); acc.y += h2f(u[1]);
          acc.z += h2f(u[2]); acc.w += h2f(u[3]);
        } else {
          acc.x += relu_f(fmaf(h2f(u[0]), rsc.x, rsh.x));
          acc.y += relu_f(fmaf(h2f(u[1]), rsc.y, rsh.y));
          acc.z += relu_f(fmaf(h2f(u[2]), rsc.z, rsh.z));
          acc.w += relu_f(fmaf(h2f(u[3]), rsc.w, rsh.w));
        }
      };
      const us4 u0 = ldE(es + 0), u1 = ldE(es + 1), u2 = ldE(es + 2);
      const us4 u3 = ldE(es + 3), u4 = ldE(es + 4), u5 = ldE(es + 5);
      if (es + 0 < ee) accum(u0);
      if (es + 1 < ee) accum(u1);
      if (es + 2 < ee) accum(u2);
      if (es + 3 < ee) accum(u3);
      if (es + 4 < ee) accum(u4);
      if (es + 5 < ee) accum(u5);
      for (int e = es + 6; e < ee; ++e) accum(ldE(e));
    }
    if (c0 < KP1) *(float4*)&buf[(hw * 4 + i) * STRK + c0] = acc;
  }
  __syncthreads();

  const int rb = wv & 1, nbase = (wv >> 1) * 64;
  const int l15 = lane & 15, quad = lane >> 4;
  const int aoff = (rb * 16 + l15) * STRK;
  constexpr int PS1 = KP1 * 128;
  constexpr int PS2 = 128 * 128;
  constexpr float INVL = 1.0f / 2048.0f;

  // ---- mm1 (MFMA f16x2)
  f32x4 am1[4] = {}, ac1[4] = {};
  for (int ks = 0; ks < KP1 / 32; ++ks) {
    const int k0 = ks * 32;
    const float4 xa = *(const float4*)&buf[aoff + k0 + quad * 8];
    const float4 xb = *(const float4*)&buf[aoff + k0 + quad * 8 + 4];
    f16x8 Ah, Al;
    {
      const float xv[8] = {xa.x, xa.y, xa.z, xa.w, xb.x, xb.y, xb.z, xb.w};
#pragma unroll
      for (int j = 0; j < 8; ++j) {
        _Float16 h, l;
        split2h(xv[j], h, l);
        Ah[j] = h; Al[j] = l;
      }
    }
    f16x8 Bh[4], Bl[4];
#pragma unroll
    for (int ct = 0; ct < 4; ++ct) {
      const int n = nbase + ct * 16 + l15;
      const short* wp = w1s + ((long)(ks * 128 + n) << 5) + (quad << 3);
      Bh[ct] = *(const f16x8*)(wp);
      Bl[ct] = *(const f16x8*)(wp + PS1);
    }
#pragma unroll
    for (int ct = 0; ct < 4; ++ct) ac1[ct] = __builtin_amdgcn_mfma_f32_16x16x32_f16(Ah, Bl[ct], ac1[ct], 0, 0, 0);
#pragma unroll
    for (int ct = 0; ct < 4; ++ct) ac1[ct] = __builtin_amdgcn_mfma_f32_16x16x32_f16(Al, Bh[ct], ac1[ct], 0, 0, 0);
#pragma unroll
    for (int ct = 0; ct < 4; ++ct) am1[ct] = __builtin_amdgcn_mfma_f32_16x16x32_f16(Ah, Bh[ct], am1[ct], 0, 0, 0);
  }
  __syncthreads();

  // mid = relu(am + ac/2048 + b1)
#pragma unroll
  for (int ct = 0; ct < 4; ++ct) {
    const int n = nbase + ct * 16 + l15;
    const float bb = b1[n];
#pragma unroll
    for (int reg = 0; reg < 4; ++reg) {
      const int m = rb * 16 + quad * 4 + reg;
      buf[m * STRK + n] = relu_f(fmaf(ac1[ct][reg], INVL, am1[ct][reg]) + bb);
    }
  }
  __syncthreads();

  // ---- mm2 (MFMA f16x2)
  f32x4 am2[4] = {}, ac2[4] = {};
  for (int ks = 0; ks < 4; ++ks) {
    const int k0 = ks * 32;
    const float4 xa = *(const float4*)&buf[aoff + k0 + quad * 8];
    const float4 xb = *(const float4*)&buf[aoff + k0 + quad * 8 + 4];
    f16x8 Ah, Al;
    {
      const float xv[8] = {xa.x, xa.y, xa.z, xa.w, xb.x, xb.y, xb.z, xb.w};
#pragma unroll
      for (int j = 0; j < 8; ++j) {
        _Float16 h, l;
        split2h(xv[j], h, l);
        Ah[j] = h; Al[j] = l;
      }
    }
    f16x8 Bh[4], Bl[4];
#pragma unroll
    for (int ct = 0; ct < 4; ++ct) {
      const int n = nbase + ct * 16 + l15;
      const short* wp = w2s + ((long)(ks * 128 + n) << 5) + (quad << 3);
      Bh[ct] = *(const f16x8*)(wp);
      Bl[ct] = *(const f16x8*)(wp + PS2);
    }
#pragma unroll
    for (int ct = 0; ct < 4; ++ct) ac2[ct] = __builtin_amdgcn_mfma_f32_16x16x32_f16(Ah, Bl[ct], ac2[ct], 0, 0, 0);
#pragma unroll
    for (int ct = 0; ct < 4; ++ct) ac2[ct] = __builtin_amdgcn_mfma_f32_16x16x32_f16(Al, Bh[ct], ac2[ct], 0, 0, 0);
#pragma unroll
    for (int ct = 0; ct < 4; ++ct) am2[ct] = __builtin_amdgcn_mfma_f32_16x16x32_f16(Ah, Bh[ct], am2[ct], 0, 0, 0);
  }

  // barrier: ALL waves' mm2 LDS reads complete before hb overwrites buf
  __syncthreads();

  // epilogue: Oh (f16) + f16 LDS tile (for scatter) + BN stats (f32)
  unsigned short* hb = (unsigned short*)(buf + 2048);
  float cs[4], cq[4];
#pragma unroll
  for (int ct = 0; ct < 4; ++ct) {
    const int n = nbase + ct * 16 + l15;
    const float bb = b2[n];
    float s = 0.f, q = 0.f;
#pragma unroll
    for (int reg = 0; reg < 4; ++reg) {
      const int m = rb * 16 + quad * 4 + reg;
      const float o = fmaf(ac2[ct][reg], INVL, am2[ct][reg]) + bb;
      const unsigned short oh = f2h(o);
      Oh[(size_t)(base + m) * 128 + n] = oh;
      if (SCAT) hb[m * 128 + n] = oh;
      s += o;
      q = fmaf(o, o, q);
    }
    cs[ct] = s; cq[ct] = q;
  }
  __syncthreads();
  const int g = rb * 4 + quad;
#pragma unroll
  for (int ct = 0; ct < 4; ++ct) {
    const int n = nbase + ct * 16 + l15;
    buf[n * 8 + g] = cs[ct];
    buf[1024 + n * 8 + g] = cq[ct];
  }
  __syncthreads();
  if (t < HIDDEN) {
    float s = 0.f, q = 0.f;
    for (int gg = 0; gg < 8; ++gg) { s += buf[t * 8 + gg]; q += buf[1024 + t * 8 + gg]; }
    atomicAdd(&bn_sum[t], s);
    atomicAdd(&bn_sq[t], q);
  }
  if (SCAT) {
    // scatter own rows to next layer's edge buffer via CSC slab
    const int S0 = csp[base], S1 = csp[base + 32];
    for (int e = S0 + hw; e < S1; e += 8) {
      const int2 sd = csc[e];
      const us4 v = *(const us4*)&hb[(sd.x - base) * 128 + c0];
      *(us4*)&Eout[(size_t)sd.y * 128 + c0] = v;
    }
  }
}

// ---------------- a2h split-K block (atomic XA) ----------------
constexpr int A2H_K = 3000, A2H_SPLIT = 200;
__device__ __forceinline__ void a2h_block(int rb, int sp, const float* __restrict__ A,
    const float* __restrict__ W, const float* __restrict__ bias, float* __restrict__ XA,
    float* xT) {
  constexpr int STR = 18;
  const int t = threadIdx.x;
  const int row0 = rb * 16;
  const int k0 = sp * A2H_SPLIT;
  for (int i = t; i < 16 * 50; i += 256) {
    const int r = i / 50, kq = i - r * 50;
    const float4 v = *(const float4*)&A[(long)(row0 + r) * A2H_K + k0 + kq * 4];
    xT[(kq * 4 + 0) * STR + r] = v.x;
    xT[(kq * 4 + 1) * STR + r] = v.y;
    xT[(kq * 4 + 2) * STR + r] = v.z;
    xT[(kq * 4 + 3) * STR + r] = v.w;
  }
  __syncthreads();
  const int rg = t >> 5, cg = t & 31;
  const int r0 = rg * 2, j0 = cg * 4;
  float acc[2][4];
  for (int r = 0; r < 2; ++r)
    for (int c = 0; c < 4; ++c) acc[r][c] = 0.f;
  const float* Wp = W + (long)k0 * HIDDEN + j0;
  for (int k = 0; k < A2H_SPLIT; ++k) {
    const float4 w = *(const float4*)&Wp[(long)k * HIDDEN];
    const float2 x = *(const float2*)&xT[k * STR + r0];
    const float wa[4] = {w.x, w.y, w.z, w.w};
    for (int c = 0; c < 4; ++c) {
      acc[0][c] = fmaf(x.x, wa[c], acc[0][c]);
      acc[1][c] = fmaf(x.y, wa[c], acc[1][c]);
    }
  }
  if (sp == 0)
    for (int c = 0; c < 4; ++c) { acc[0][c] += bias[j0 + c]; acc[1][c] += bias[j0 + c]; }
  for (int r = 0; r < 2; ++r)
    for (int c = 0; c < 4; ++c)
      atomicAdd(&XA[(size_t)(row0 + r0 + r) * HIDDEN + j0 + c], acc[r][c]);
  __syncthreads();
}

// ---------------- fat0: gin0 (reduce Ea, scatter -> Eb) + a2h(sp 0-4) ----------------
__global__ __launch_bounds__(256, 4) void fat0_kernel(
    const float* __restrict__ x_lig, unsigned short* __restrict__ Oh,
    const int* __restrict__ row_ptr, const unsigned short* __restrict__ Ea,
    const int* __restrict__ csp, const int2* __restrict__ csc,
    unsigned short* __restrict__ Eb,
    const short* __restrict__ ws, const float* __restrict__ b1,
    const float* __restrict__ b2,
    float* __restrict__ bn_sum, float* __restrict__ bn_sq,
    const float* __restrict__ a2h, const float* __restrict__ a1W,
    const float* __restrict__ a1b, float* __restrict__ XA) {
  __shared__ __align__(16) float buf[32 * STRK];
  const int b = blockIdx.x;
  if (b < NNODES / 32) {
    gin_block<96, true, true>(b, x_lig, Oh, row_ptr, Ea, csp, csc, Eb,
                              ws, b1, ws + 24576, b2,
                              nullptr, nullptr, nullptr, nullptr,
                              bn_sum, bn_sq, buf);
  } else {
    const int q = b - NNODES / 32;
    a2h_block(q & 127, q >> 7, a2h, a1W, a1b, XA, buf);
  }
}

// ---------------- gin wrapper (layers 1,2) + a2h tail ----------------
template<bool SCAT>
__global__ __launch_bounds__(256, 4) void gin_kernel(
    unsigned short* __restrict__ Oh, const int* __restrict__ row_ptr,
    const unsigned short* __restrict__ Ein,
    const int* __restrict__ csp, const int2* __restrict__ csc,
    unsigned short* __restrict__ Eout,
    const short* __restrict__ w1s, const float* __restrict__ b1,
    const short* __restrict__ w2s, const float* __restrict__ b2,
    const float* __restrict__ psum, const float* __restrict__ psq,
    const float* __restrict__ bg, const float* __restrict__ bb2,
    float* __restrict__ bn_sum, float* __restrict__ bn_sq,
    const float* __restrict__ a2h, const float* __restrict__ a1W,
    const float* __restrict__ a1b, float* __restrict__ XA, int sp_base) {
  __shared__ __align__(16) float buf[32 * STRK];
  const int b = blockIdx.x;
  if (b < NNODES / 32) {
    gin_block<128, false, SCAT>(b, nullptr, Oh, row_ptr, Ein, csp, csc, Eout,
                                w1s, b1, w2s, b2,
                                psum, psq, bg, bb2,
                                bn_sum, bn_sq, buf);
  } else {
    const int q = b - NNODES / 32;
    a2h_block(q & 127, sp_base + (q >> 7), a2h, a1W, a1b, XA, buf);
  }
}

// ---------------- mega-head ----------------
__global__ __launch_bounds__(256) void head_kernel(
    const unsigned short* __restrict__ Oh, const int* __restrict__ gp,
    const float* __restrict__ psum, const float* __restrict__ psq,
    const float* __restrict__ bg, const float* __restrict__ bb2,
    const float* __restrict__ XP32, const float* __restrict__ XA,
    const float* __restrict__ ligW, const float* __restrict__ ligb,
    const float* __restrict__ protW, const float* __restrict__ protb,
    const float* __restrict__ a2W, const float* __restrict__ a2b,
    const float* __restrict__ c1W, const float* __restrict__ c1b,
    const float* __restrict__ c2W, const float* __restrict__ c2b,
    const float* __restrict__ oW, const float* __restrict__ ob,
    float* __restrict__ out) {
  __shared__ float Ps[4][128];
  __shared__ float XAs[4][128];
  __shared__ float XPs[4][32];
  __shared__ float XCs[4][384];
  __shared__ float XC2s[4][256];
  __shared__ float XC3s[4][128];
  const int t = threadIdx.x;
  const int g0 = blockIdx.x * 4;

  // phase A: pool (inline BN of layer 2, f16 O) + stage XA(relu) / XP
  {
    const int sub = t >> 6, lane = t & 63;
    const int g = g0 + sub;
    const int f0 = lane, f1 = lane + 64;
    float mu0 = psum[f0] * (1.0f / NNODES);
    float va0 = fmaxf(psq[f0] * (1.0f / NNODES) - mu0 * mu0, 0.0f);
    float sc0 = bg[f0] / sqrtf(va0 + 1e-5f);
    float sh0 = bb2[f0] - mu0 * sc0;
    float mu1 = psum[f1] * (1.0f / NNODES);
    float va1 = fmaxf(psq[f1] * (1.0f / NNODES) - mu1 * mu1, 0.0f);
    float sc1 = bg[f1] / sqrtf(va1 + 1e-5f);
    float sh1 = bb2[f1] - mu1 * sc1;
    const int n0 = gp[g], n1 = gp[g + 1];
    float a0 = 0.f, a1 = 0.f;
    for (int n = n0; n < n1; ++n) {
      a0 += relu_f(fmaf(h2f(Oh[(size_t)n * HIDDEN + f0]), sc0, sh0));
      a1 += relu_f(fmaf(h2f(Oh[(size_t)n * HIDDEN + f1]), sc1, sh1));
    }
    Ps[sub][f0] = a0;
    Ps[sub][f1] = a1;
    for (int i = t; i < 512; i += 256) XAs[i >> 7][i & 127] = relu_f(XA[g0 * 128 + i]);
    for (int i = t; i < 128; i += 256) XPs[i >> 5][i & 31] = XP32[g0 * 32 + i];
  }
  __syncthreads();

  // phase B: lig / prot / a2 -> XCs
  {
    const int j = t & 127, pr = t >> 7;
    const int s0 = pr * 2, s1 = pr * 2 + 1;
    float L0 = ligb[j], L1 = L0;
    float A0 = a2b[j], A1 = A0;
    for (int k = 0; k < 128; ++k) {
      const float wl = ligW[k * 128 + j];
      const float wa = a2W[k * 128 + j];
      L0 = fmaf(Ps[s0][k], wl, L0); L1 = fmaf(Ps[s1][k], wl, L1);
      A0 = fmaf(XAs[s0][k], wa, A0); A1 = fmaf(XAs[s1][k], wa, A1);
    }
    float P0 = protb[j], P1 = P0;
    for (int k = 0; k < 32; ++k) {
      const float wp = protW[k * 128 + j];
      P0 = fmaf(XPs[s0][k], wp, P0); P1 = fmaf(XPs[s1][k], wp, P1);
    }
    XCs[s0][j] = relu_f(L0);        XCs[s1][j] = relu_f(L1);
    XCs[s0][128 + j] = relu_f(P0);  XCs[s1][128 + j] = relu_f(P1);
    XCs[s0][256 + j] = relu_f(A0);  XCs[s1][256 + j] = relu_f(A1);
  }
  __syncthreads();

  // phase C: c1 (384 -> 256)
  {
    const int j = t;
    float a[4];
    const float bv = c1b[j];
    for (int s = 0; s < 4; ++s) a[s] = bv;
    for (int k = 0; k < 384; ++k) {
      const float w = c1W[k * 256 + j];
      for (int s = 0; s < 4; ++s) a[s] = fmaf(XCs[s][k], w, a[s]);
    }
    for (int s = 0; s < 4; ++s) XC2s[s][j] = relu_f(a[s]);
  }
  __syncthreads();

  // phase D: c2 (256 -> 128)
  {
    const int j = t & 127, pr = t >> 7;
    const int s0 = pr * 2, s1 = pr * 2 + 1;
    float a0 = c2b[j], a1 = a0;
    for (int k = 0; k < 256; ++k) {
      const float w = c2W[k * 128 + j];
      a0 = fmaf(XC2s[s0][k], w, a0);
      a1 = fmaf(XC2s[s1][k], w, a1);
    }
    XC3s[s0][j] = relu_f(a0);
    XC3s[s1][j] = relu_f(a1);
  }
  __syncthreads();

  // phase E: out (128 -> 1)
  {
    const int w = t >> 6, lane = t & 63;
    float p = XC3s[w][lane] * oW[lane] + XC3s[w][lane + 64] * oW[lane + 64];
    for (int off = 32; off >= 1; off >>= 1) p += __shfl_down(p, off);
    if (lane == 0) out[g0 + w] = p + ob[0];
  }
}

extern "C" void kernel_launch(void* const* d_in, const int* in_sizes, int n_in,
                              void* d_out, int out_size, void* d_ws, size_t ws_size,
                              hipStream_t stream) {
  const float* x_lig = (const float*)d_in[0];
  const float* pseq  = (const float*)d_in[1];
  const float* a2h   = (const float*)d_in[2];
  const int*   ei    = (const int*)d_in[3];
  const int*   batch = (const int*)d_in[4];
  const float* ginW1[3] = {(const float*)d_in[5],  (const float*)d_in[11], (const float*)d_in[17]};
  const float* ginb1[3] = {(const float*)d_in[6],  (const float*)d_in[12], (const float*)d_in[18]};
  const float* ginW2[3] = {(const float*)d_in[7],  (const float*)d_in[13], (const float*)d_in[19]};
  const float* ginb2[3] = {(const float*)d_in[8],  (const float*)d_in[14], (const float*)d_in[20]};
  const float* bng[3]   = {(const float*)d_in[9],  (const float*)d_in[15], (const float*)d_in[21]};
  const float* bnb[3]   = {(const float*)d_in[10], (const float*)d_in[16], (const float*)d_in[22]};
  const float* ligW  = (const float*)d_in[23]; const float* ligb  = (const float*)d_in[24];
  const float* convk = (const float*)d_in[25]; const float* convb = (const float*)d_in[26];
  const float* protW = (const float*)d_in[27]; const float* protb = (const float*)d_in[28];
  const float* a1W   = (const float*)d_in[29]; const float* a1b   = (const float*)d_in[30];
  const float* a2W   = (const float*)d_in[31]; const float* a2b   = (const float*)d_in[32];
  const float* c1W   = (const float*)d_in[33]; const float* c1b   = (const float*)d_in[34];
  const float* c2W   = (const float*)d_in[35]; const float* c2b   = (const float*)d_in[36];
  const float* oW    = (const float*)d_in[37]; const float* ob    = (const float*)d_in[38];

  char* base = (char*)d_ws;
  size_t off = 0;
  auto alloc = [&](size_t bytes) -> char* {
    char* p = base + off;
    off = (off + bytes + 511) & ~size_t(511);
    return p;
  };
  int*   counts_d = (int*)alloc(NNODES * 4);
  int*   counts_s = (int*)alloc(NNODES * 4);
  int*   gcounts  = (int*)alloc(NGRAPHS * 4);
  float* bn_sum   = (float*)alloc(3 * 128 * 4);
  float* bn_sq    = (float*)alloc(3 * 128 * 4);
  float* XA       = (float*)alloc((size_t)NGRAPHS * HIDDEN * 4);
  const size_t zero_bytes = off;
  short* wsplit   = (short*)alloc(188416 * 2);
  int*   row_ptr  = (int*)alloc((NNODES + 1) * 4);
  int*   nxt_d    = (int*)alloc(NNODES * 4);
  int*   nxt_s    = (int*)alloc(NNODES * 4);
  int*   csp      = (int*)alloc((NNODES + 1) * 4);
  int*   gptr     = (int*)alloc((NGRAPHS + 1) * 4);
  int*   bsA      = (int*)alloc(401 * 4);
  int*   bsS      = (int*)alloc(401 * 4);
  int*   bsB      = (int*)alloc(9 * 4);
  int2*  csc      = (int2*)alloc((size_t)NEDGES * 8);
  float* XP32     = (float*)alloc(NGRAPHS * 32 * 4);
  unsigned short* Oh  = (unsigned short*)alloc((size_t)NNODES * 128 * 2);
  unsigned short* ER1 = (unsigned short*)alloc((size_t)NEDGES * 128 * 2); // se0 (80w) / gin1-out (128w)
  unsigned short* ER2 = (unsigned short*)alloc((size_t)NEDGES * 128 * 2); // fat0-out
  (void)ws_size; (void)in_sizes; (void)n_in; (void)out_size;

  hipMemsetAsync(d_ws, 0, zero_bytes, stream);

  prep_kernel<<<1600 + 1600 + 400 + 736, 256, 0, stream>>>(
      ei, batch, counts_d, counts_s, gcounts,
      ginW1[0], ginW2[0], ginW1[1], ginW2[1], ginW1[2], ginW2[2], wsplit);
  scan_block3_kernel<<<2 * (NNODES / 256) + NGRAPHS / 256, 256, 0, stream>>>(
      counts_d, row_ptr, bsA, counts_s, nxt_s, bsS, gcounts, gptr, bsB);
  scan_top3_kernel<<<3, 1024, 0, stream>>>(bsA, bsS, bsB);
  scan_add3_kernel<<<2 * (NNODES / 256) + NGRAPHS / 256, 256, 0, stream>>>(
      row_ptr, bsA, nxt_d, nxt_s, bsS, csp, gptr, bsB);
  scatterAB_kernel<<<(NEDGES + 255) / 256, 256, 0, stream>>>(ei, nxt_d, nxt_s, csc);

  // E0 scatter (+ conv)
  se0_kernel<<<NEDGES / 64 + NGRAPHS, 256, 0, stream>>>(
      x_lig, csc, ER1, pseq, convk, convb, XP32);

  // layer 0: reduce ER1 (80w), scatter raw O0 -> ER2 (+ a2h sp 0-4)
  fat0_kernel<<<NNODES / 32 + (NGRAPHS / 16) * 5, 256, 0, stream>>>(
      x_lig, Oh, row_ptr, ER1, csp, csc, ER2, wsplit, ginb1[0], ginb2[0],
      bn_sum, bn_sq, a2h, a1W, a1b, XA);

  // layer 1: reduce ER2 (BN0 on consume), scatter raw O1 -> ER1 (+ a2h sp 5-9)
  gin_kernel<true><<<NNODES / 32 + (NGRAPHS / 16) * 5, 256, 0, stream>>>(
      Oh, row_ptr, ER2, csp, csc, ER1,
      wsplit + 57344, ginb1[1], wsplit + 90112, ginb2[1],
      bn_sum, bn_sq, bng[0], bnb[0],
      bn_sum + 128, bn_sq + 128, a2h, a1W, a1b, XA, 5);

  // layer 2: reduce ER1 (BN1 on consume), no scatter (+ a2h sp 10-14)
  gin_kernel<false><<<NNODES / 32 + (NGRAPHS / 16) * 5, 256, 0, stream>>>(
      Oh, row_ptr, ER1, csp, csc, nullptr,
      wsplit + 122880, ginb1[2], wsplit + 155648, ginb2[2],
      bn_sum + 128, bn_sq + 128, bng[1], bnb[1],
      bn_sum + 256, bn_sq + 256, a2h, a1W, a1b, XA, 10);

  head_kernel<<<NGRAPHS / 4, 256, 0, stream>>>(Oh, gptr,
      bn_sum + 256, bn_sq + 256, bng[2], bnb[2], XP32, XA,
      ligW, ligb, protW, protb, a2W, a2b, c1W, c1b, c2W, c2b, oW, ob, (float*)d_out);
}

// Round 8
// 686.630 us; speedup vs baseline: 1.6874x; 1.2082x over previous
//
#include <hip/hip_runtime.h>
#include <hip/hip_fp16.h>
#include <math.h>

constexpr int NNODES  = 102400;
constexpr int NEDGES  = 409600;
constexpr int NGRAPHS = 2048;
constexpr int HIDDEN  = 128;

typedef __attribute__((ext_vector_type(8))) _Float16 f16x8;
typedef __attribute__((ext_vector_type(4))) float f32x4;
typedef __attribute__((ext_vector_type(4))) unsigned short us4;

__device__ __forceinline__ float relu_f(float v) { return fmaxf(v, 0.0f); }
__device__ __forceinline__ float h2f(unsigned short s) {
  return (float)__builtin_bit_cast(_Float16, s);
}
__device__ __forceinline__ unsigned short f2h(float x) {
  return __builtin_bit_cast(unsigned short, (_Float16)x);
}
// 2-way f16 split with scaled lo plane: x ~= hi + lo * 2^-11
__device__ __forceinline__ void split2h(float x, _Float16& h, _Float16& l) {
  h = (_Float16)x;
  float r = x - (float)h;
  l = (_Float16)(r * 2048.0f);
}

// ---------------- prep: histograms + weight-split (f16x2) ----------------
__global__ void prep_kernel(const int* __restrict__ ei, const int* __restrict__ batch,
                            int* __restrict__ counts, int* __restrict__ gcounts,
                            const float* __restrict__ W10, const float* __restrict__ W20,
                            const float* __restrict__ W11, const float* __restrict__ W21,
                            const float* __restrict__ W12, const float* __restrict__ W22,
                            short* __restrict__ ws) {
  int b = blockIdx.x;
  if (b < NEDGES / 256) {
    atomicAdd(&counts[ei[NEDGES + b * 256 + threadIdx.x]], 1);
    return;
  }
  if (b < NEDGES / 256 + NNODES / 256) {
    atomicAdd(&gcounts[batch[(b - NEDGES / 256) * 256 + threadIdx.x]], 1);
    return;
  }
  int bw = b - (NEDGES / 256 + NNODES / 256);
  int n = threadIdx.x;
  if (n >= 128) return;
  const float* src; long base; int k, realK, KP;
  if (bw < 96) {
    src = W10; base = 0; k = bw; realK = 78; KP = 96;
  } else {
    int q = bw - 96;
    int mat = q >> 7;
    k = q & 127; realK = 128; KP = 128;
    const float* srcs[5] = {W20, W11, W21, W12, W22};
    const long bases[5] = {24576, 57344, 90112, 122880, 155648};
    src = srcs[mat]; base = bases[mat];
  }
  float x = (k < realK) ? src[k * 128 + n] : 0.0f;
  _Float16 h, l;
  split2h(x, h, l);
  long e = base + ((long)(k >> 5) * 128 + n) * 32 + (k & 31);
  long ps = (long)KP * 128;
  ws[e] = __builtin_bit_cast(short, h);
  ws[e + ps] = __builtin_bit_cast(short, l);
}

// ---------------- merged scans ----------------
__device__ __forceinline__ void scan_block_body(const int* in, int n, int* out_excl,
                                                int* bsums, int lb) {
  __shared__ int s[256];
  int t = threadIdx.x;
  int i = lb * 256 + t;
  int v = (i < n) ? in[i] : 0;
  s[t] = v;
  __syncthreads();
  for (int off = 1; off < 256; off <<= 1) {
    int x = (t >= off) ? s[t - off] : 0;
    __syncthreads();
    s[t] += x;
    __syncthreads();
  }
  if (i < n) out_excl[i] = s[t] - v;
  if (t == 255) bsums[lb] = s[255];
}

__global__ void scan_block2_kernel(const int* __restrict__ counts, int* __restrict__ row_ptr,
                                   int* __restrict__ bsumsA, const int* __restrict__ gcounts,
                                   int* __restrict__ gptr, int* __restrict__ bsumsB) {
  int b = blockIdx.x;
  if (b < NNODES / 256) scan_block_body(counts, NNODES, row_ptr, bsumsA, b);
  else scan_block_body(gcounts, NGRAPHS, gptr, bsumsB, b - NNODES / 256);
}

__global__ void scan_top2_kernel(int* __restrict__ bsumsA, int* __restrict__ bsumsB) {
  __shared__ int s[1024];
  int* bs = (blockIdx.x == 0) ? bsumsA : bsumsB;
  int nb  = (blockIdx.x == 0) ? (NNODES / 256) : (NGRAPHS / 256);
  int t = threadIdx.x;
  int v = (t < nb) ? bs[t] : 0;
  s[t] = v;
  __syncthreads();
  for (int off = 1; off < 1024; off <<= 1) {
    int x = (t >= off) ? s[t - off] : 0;
    __syncthreads();
    s[t] += x;
    __syncthreads();
  }
  if (t < nb) bs[t] = s[t] - v;
  if (t == 1023) bs[nb] = s[1023];
}

__global__ void scan_add2_kernel(int* __restrict__ row_ptr, const int* __restrict__ bsumsA,
                                 int* __restrict__ nxt, int* __restrict__ gptr,
                                 const int* __restrict__ bsumsB) {
  int b = blockIdx.x, t = threadIdx.x;
  if (b < NNODES / 256) {
    int i = b * 256 + t;
    int v = row_ptr[i] + bsumsA[b];
    row_ptr[i] = v;
    nxt[i] = v;
    if (i == 0) row_ptr[NNODES] = bsumsA[NNODES / 256];
  } else {
    int lb = b - NNODES / 256;
    int i = lb * 256 + t;
    gptr[i] += bsumsB[lb];
    if (i == 0) gptr[NGRAPHS] = bsumsB[NGRAPHS / 256];
  }
}

__global__ void scatter_kernel(const int* __restrict__ ei, int* __restrict__ nxt,
                               int* __restrict__ csr_src) {
  int e = blockIdx.x * blockDim.x + threadIdx.x;
  if (e < NEDGES) {
    int s = ei[e];
    int d = ei[NEDGES + e];
    int pos = atomicAdd(&nxt[d], 1);
    csr_src[pos] = s;
  }
}

// ---------------- GIN block body ----------------
// Gather (R0 structure): depth-2 software-pipelined edge stream per slot.
// Layers 1/2: f16 rows (us4/lane, 256B/row) from Oh, BN+ReLU on consume.
// Layer 0:    f32 float2 walker on x_lig (DIN=78).
// MFMA mm1/mm2 via f16x2 split (hi + 2^-11*lo). O stored as raw f16.
constexpr int STRK = 132;
template<int DIN, int KP1, bool XF, bool G4>
__device__ __forceinline__ void gin_block(
    int bid, const float* __restrict__ Xf, const unsigned short* __restrict__ Xh,
    unsigned short* __restrict__ OhOut,
    const int* __restrict__ row_ptr, const int* __restrict__ csr_src,
    const short* __restrict__ w1s, const float* __restrict__ b1,
    const short* __restrict__ w2s, const float* __restrict__ b2,
    const float* __restrict__ psum, const float* __restrict__ psq,
    const float* __restrict__ bg, const float* __restrict__ bb2,
    float* __restrict__ bn_sum, float* __restrict__ bn_sq,
    float* buf) {
  const int t = threadIdx.x;
  const int wv = t >> 6, lane = t & 63;
  const int base = bid * 32;

  if (G4) {
    // ---- f16 gather, depth-2 pipelined: lane = (row-half, feature-quad)
    const int q = lane & 31, half = lane >> 5;
    const int f = 4 * q;
    float sc[4], sh[4];
#pragma unroll
    for (int c = 0; c < 4; ++c) {
      float mu = psum[f + c] * (1.0f / NNODES);
      float va = fmaxf(psq[f + c] * (1.0f / NNODES) - mu * mu, 0.0f);
      sc[c] = bg[f + c] / sqrtf(va + 1e-5f);
      sh[c] = bb2[f + c] - mu * sc[c];
    }
    float4 acc[4];
    us4 u0[4];
    int e[4], eend[4], i0[4], i1[4];
#pragma unroll
    for (int p = 0; p < 4; ++p) {
      const int node = base + wv * 8 + 2 * p + half;
      e[p] = row_ptr[node];
      eend[p] = row_ptr[node + 1];
      const us4 s = *(const us4*)&Xh[(size_t)node * 128 + f];
      acc[p].x = relu_f(fmaf(h2f(s[0]), sc[0], sh[0]));
      acc[p].y = relu_f(fmaf(h2f(s[1]), sc[1], sh[1]));
      acc[p].z = relu_f(fmaf(h2f(s[2]), sc[2], sh[2]));
      acc[p].w = relu_f(fmaf(h2f(s[3]), sc[3], sh[3]));
      i0[p] = (e[p] < eend[p]) ? csr_src[e[p]] : -1;
      i1[p] = (e[p] + 1 < eend[p]) ? csr_src[e[p] + 1] : -1;
    }
#pragma unroll
    for (int p = 0; p < 4; ++p)
      if (i0[p] >= 0) u0[p] = *(const us4*)&Xh[(size_t)i0[p] * 128 + f];
    bool any = (i0[0] >= 0) || (i0[1] >= 0) || (i0[2] >= 0) || (i0[3] >= 0);
    while (any) {
      us4 u1[4];
      int i2[4];
#pragma unroll
      for (int p = 0; p < 4; ++p)
        if (i1[p] >= 0) u1[p] = *(const us4*)&Xh[(size_t)i1[p] * 128 + f];
#pragma unroll
      for (int p = 0; p < 4; ++p)
        i2[p] = (e[p] + 2 < eend[p]) ? csr_src[e[p] + 2] : -1;
      any = false;
#pragma unroll
      for (int p = 0; p < 4; ++p) {
        if (i0[p] >= 0) {
          acc[p].x += relu_f(fmaf(h2f(u0[p][0]), sc[0], sh[0]));
          acc[p].y += relu_f(fmaf(h2f(u0[p][1]), sc[1], sh[1]));
          acc[p].z += relu_f(fmaf(h2f(u0[p][2]), sc[2], sh[2]));
          acc[p].w += relu_f(fmaf(h2f(u0[p][3]), sc[3], sh[3]));
        }
        ++e[p];
        i0[p] = i1[p]; i1[p] = i2[p]; u0[p] = u1[p];
        any = any || (i0[p] >= 0);
      }
    }
#pragma unroll
    for (int p = 0; p < 4; ++p)
      *(float4*)&buf[(wv * 8 + 2 * p + half) * STRK + f] = acc[p];
  } else {
    // ---- float2 gather (layer 0, DIN=78, KP=96), depth-2 pipelined
    const int fp = 2 * lane;
    if (fp < KP1) {
      if (fp < DIN) {
        for (int g = 0; g < 2; ++g) {
          const int rbase = wv * 8 + g * 4;
          float a0[4], a1[4];
          float2 u0[4];
          int e[4], eend[4], i0[4], i1[4];
#pragma unroll
          for (int r = 0; r < 4; ++r) {
            const int node = base + rbase + r;
            e[r] = row_ptr[node];
            eend[r] = row_ptr[node + 1];
            const float2 s = *(const float2*)&Xf[(long)node * DIN + fp];
            a0[r] = s.x; a1[r] = s.y;
            i0[r] = (e[r] < eend[r]) ? csr_src[e[r]] : -1;
            i1[r] = (e[r] + 1 < eend[r]) ? csr_src[e[r] + 1] : -1;
          }
#pragma unroll
          for (int r = 0; r < 4; ++r)
            if (i0[r] >= 0) u0[r] = *(const float2*)&Xf[(long)i0[r] * DIN + fp];
          bool any = (i0[0] >= 0) || (i0[1] >= 0) || (i0[2] >= 0) || (i0[3] >= 0);
          while (any) {
            float2 u1[4];
            int i2[4];
#pragma unroll
            for (int r = 0; r < 4; ++r)
              if (i1[r] >= 0) u1[r] = *(const float2*)&Xf[(long)i1[r] * DIN + fp];
#pragma unroll
            for (int r = 0; r < 4; ++r)
              i2[r] = (e[r] + 2 < eend[r]) ? csr_src[e[r] + 2] : -1;
            any = false;
#pragma unroll
            for (int r = 0; r < 4; ++r) {
              if (i0[r] >= 0) {
                a0[r] += u0[r].x;
                a1[r] += u0[r].y;
              }
              ++e[r];
              i0[r] = i1[r]; i1[r] = i2[r]; u0[r] = u1[r];
              any = any || (i0[r] >= 0);
            }
          }
#pragma unroll
          for (int r = 0; r < 4; ++r)
            *(float2*)&buf[(rbase + r) * STRK + fp] = make_float2(a0[r], a1[r]);
        }
      } else {
        for (int r = 0; r < 8; ++r)
          *(float2*)&buf[(wv * 8 + r) * STRK + fp] = make_float2(0.f, 0.f);
      }
    }
  }
  __syncthreads();

  const int rb = wv & 1, nbase = (wv >> 1) * 64;
  const int l15 = lane & 15, quad = lane >> 4;
  const int aoff = (rb * 16 + l15) * STRK;
  constexpr int PS1 = KP1 * 128;
  constexpr int PS2 = 128 * 128;
  constexpr float INVL = 1.0f / 2048.0f;

  // ---- mm1 (MFMA f16x2)
  f32x4 am1[4] = {}, ac1[4] = {};
  for (int ks = 0; ks < KP1 / 32; ++ks) {
    const int k0 = ks * 32;
    const float4 xa = *(const float4*)&buf[aoff + k0 + quad * 8];
    const float4 xb = *(const float4*)&buf[aoff + k0 + quad * 8 + 4];
    f16x8 Ah, Al;
    {
      const float xv[8] = {xa.x, xa.y, xa.z, xa.w, xb.x, xb.y, xb.z, xb.w};
#pragma unroll
      for (int j = 0; j < 8; ++j) {
        _Float16 h, l;
        split2h(xv[j], h, l);
        Ah[j] = h; Al[j] = l;
      }
    }
    f16x8 Bh[4], Bl[4];
#pragma unroll
    for (int ct = 0; ct < 4; ++ct) {
      const int n = nbase + ct * 16 + l15;
      const short* wp = w1s + ((long)(ks * 128 + n) << 5) + (quad << 3);
      Bh[ct] = *(const f16x8*)(wp);
      Bl[ct] = *(const f16x8*)(wp + PS1);
    }
#pragma unroll
    for (int ct = 0; ct < 4; ++ct) ac1[ct] = __builtin_amdgcn_mfma_f32_16x16x32_f16(Ah, Bl[ct], ac1[ct], 0, 0, 0);
#pragma unroll
    for (int ct = 0; ct < 4; ++ct) ac1[ct] = __builtin_amdgcn_mfma_f32_16x16x32_f16(Al, Bh[ct], ac1[ct], 0, 0, 0);
#pragma unroll
    for (int ct = 0; ct < 4; ++ct) am1[ct] = __builtin_amdgcn_mfma_f32_16x16x32_f16(Ah, Bh[ct], am1[ct], 0, 0, 0);
  }
  __syncthreads();

  // mid = relu(am + ac/2048 + b1), stored [m][j]
#pragma unroll
  for (int ct = 0; ct < 4; ++ct) {
    const int n = nbase + ct * 16 + l15;
    const float bb = b1[n];
#pragma unroll
    for (int reg = 0; reg < 4; ++reg) {
      const int m = rb * 16 + quad * 4 + reg;
      buf[m * STRK + n] = relu_f(fmaf(ac1[ct][reg], INVL, am1[ct][reg]) + bb);
    }
  }
  __syncthreads();

  // ---- mm2 (MFMA f16x2)
  f32x4 am2[4] = {}, ac2[4] = {};
  for (int ks = 0; ks < 4; ++ks) {
    const int k0 = ks * 32;
    const float4 xa = *(const float4*)&buf[aoff + k0 + quad * 8];
    const float4 xb = *(const float4*)&buf[aoff + k0 + quad * 8 + 4];
    f16x8 Ah, Al;
    {
      const float xv[8] = {xa.x, xa.y, xa.z, xa.w, xb.x, xb.y, xb.z, xb.w};
#pragma unroll
      for (int j = 0; j < 8; ++j) {
        _Float16 h, l;
        split2h(xv[j], h, l);
        Ah[j] = h; Al[j] = l;
      }
    }
    f16x8 Bh[4], Bl[4];
#pragma unroll
    for (int ct = 0; ct < 4; ++ct) {
      const int n = nbase + ct * 16 + l15;
      const short* wp = w2s + ((long)(ks * 128 + n) << 5) + (quad << 3);
      Bh[ct] = *(const f16x8*)(wp);
      Bl[ct] = *(const f16x8*)(wp + PS2);
    }
#pragma unroll
    for (int ct = 0; ct < 4; ++ct) ac2[ct] = __builtin_amdgcn_mfma_f32_16x16x32_f16(Ah, Bl[ct], ac2[ct], 0, 0, 0);
#pragma unroll
    for (int ct = 0; ct < 4; ++ct) ac2[ct] = __builtin_amdgcn_mfma_f32_16x16x32_f16(Al, Bh[ct], ac2[ct], 0, 0, 0);
#pragma unroll
    for (int ct = 0; ct < 4; ++ct) am2[ct] = __builtin_amdgcn_mfma_f32_16x16x32_f16(Ah, Bh[ct], am2[ct], 0, 0, 0);
  }

  // epilogue: Oh (f16) + BN stats
  float cs[4], cq[4];
#pragma unroll
  for (int ct = 0; ct < 4; ++ct) {
    const int n = nbase + ct * 16 + l15;
    const float bb = b2[n];
    float s = 0.f, q = 0.f;
#pragma unroll
    for (int reg = 0; reg < 4; ++reg) {
      const int m = rb * 16 + quad * 4 + reg;
      const float o = fmaf(ac2[ct][reg], INVL, am2[ct][reg]) + bb;
      OhOut[(size_t)(base + m) * HIDDEN + n] = f2h(o);
      s += o;
      q = fmaf(o, o, q);
    }
    cs[ct] = s; cq[ct] = q;
  }
  __syncthreads();
  const int g = rb * 4 + quad;
#pragma unroll
  for (int ct = 0; ct < 4; ++ct) {
    const int n = nbase + ct * 16 + l15;
    buf[n * 8 + g] = cs[ct];
    buf[1024 + n * 8 + g] = cq[ct];
  }
  __syncthreads();
  if (t < HIDDEN) {
    float s = 0.f, q = 0.f;
    for (int gg = 0; gg < 8; ++gg) { s += buf[t * 8 + gg]; q += buf[1024 + t * 8 + gg]; }
    atomicAdd(&bn_sum[t], s);
    atomicAdd(&bn_sq[t], q);
  }
}

// ---------------- a2h split-K block (atomic XA) ----------------
constexpr int A2H_K = 3000, A2H_SPLIT = 200;
__device__ __forceinline__ void a2h_block(int rb, int sp, const float* __restrict__ A,
    const float* __restrict__ W, const float* __restrict__ bias, float* __restrict__ XA,
    float* xT) {
  constexpr int STR = 18;
  const int t = threadIdx.x;
  const int row0 = rb * 16;
  const int k0 = sp * A2H_SPLIT;
  for (int i = t; i < 16 * 50; i += 256) {
    const int r = i / 50, kq = i - r * 50;
    const float4 v = *(const float4*)&A[(long)(row0 + r) * A2H_K + k0 + kq * 4];
    xT[(kq * 4 + 0) * STR + r] = v.x;
    xT[(kq * 4 + 1) * STR + r] = v.y;
    xT[(kq * 4 + 2) * STR + r] = v.z;
    xT[(kq * 4 + 3) * STR + r] = v.w;
  }
  __syncthreads();
  const int rg = t >> 5, cg = t & 31;
  const int r0 = rg * 2, j0 = cg * 4;
  float acc[2][4];
  for (int r = 0; r < 2; ++r)
    for (int c = 0; c < 4; ++c) acc[r][c] = 0.f;
  const float* Wp = W + (long)k0 * HIDDEN + j0;
  for (int k = 0; k < A2H_SPLIT; ++k) {
    const float4 w = *(const float4*)&Wp[(long)k * HIDDEN];
    const float2 x = *(const float2*)&xT[k * STR + r0];
    const float wa[4] = {w.x, w.y, w.z, w.w};
    for (int c = 0; c < 4; ++c) {
      acc[0][c] = fmaf(x.x, wa[c], acc[0][c]);
      acc[1][c] = fmaf(x.y, wa[c], acc[1][c]);
    }
  }
  if (sp == 0)
    for (int c = 0; c < 4; ++c) { acc[0][c] += bias[j0 + c]; acc[1][c] += bias[j0 + c]; }
  for (int r = 0; r < 2; ++r)
    for (int c = 0; c < 4; ++c)
      atomicAdd(&XA[(size_t)(row0 + r0 + r) * HIDDEN + j0 + c], acc[r][c]);
}

// ---------------- conv block ----------------
__device__ __forceinline__ void conv_block(int g, const float* __restrict__ PS,
    const float* __restrict__ CK, const float* __restrict__ CB, float* __restrict__ XP,
    float* seq) {
  const int t = threadIdx.x;
  for (int i = t; i < 1000; i += 256) seq[i] = PS[g * 1000 + i];
  __syncthreads();
  const int pl = t & 31, cgp = t >> 5;
  float kr[4][8];
  for (int cc = 0; cc < 4; ++cc)
    for (int k = 0; k < 8; ++k) kr[cc][k] = CK[(cgp * 4 + cc) * 8 + k];
  float m[4] = {-1e30f, -1e30f, -1e30f, -1e30f};
  for (int i = 0; i < 32; ++i) {
    int p = pl + 32 * i;
    if (p < 993) {
      float sv[8];
      for (int k = 0; k < 8; ++k) sv[k] = seq[p + k];
      for (int cc = 0; cc < 4; ++cc) {
        float s = 0.f;
        for (int k = 0; k < 8; ++k) s = fmaf(sv[k], kr[cc][k], s);
        m[cc] = fmaxf(m[cc], s);
      }
    }
  }
  for (int off = 16; off >= 1; off >>= 1)
    for (int cc = 0; cc < 4; ++cc) m[cc] = fmaxf(m[cc], __shfl_xor(m[cc], off));
  if (pl == 0)
    for (int cc = 0; cc < 4; ++cc)
      XP[g * 32 + cgp * 4 + cc] = relu_f(m[cc] + CB[cgp * 4 + cc]);
}

// ---------------- fat0: gin0 + a2h(sp 0-4) + conv ----------------
__global__ __launch_bounds__(256, 4) void fat0_kernel(
    const float* __restrict__ x_lig, unsigned short* __restrict__ Oh0,
    const int* __restrict__ row_ptr, const int* __restrict__ csr_src,
    const short* __restrict__ ws, const float* __restrict__ b1,
    const float* __restrict__ b2,
    float* __restrict__ bn_sum, float* __restrict__ bn_sq,
    const float* __restrict__ a2h, const float* __restrict__ a1W,
    const float* __restrict__ a1b, float* __restrict__ XA,
    const float* __restrict__ pseq, const float* __restrict__ convk,
    const float* __restrict__ convb, float* __restrict__ XP32) {
  __shared__ __align__(16) float buf[32 * STRK];
  const int b = blockIdx.x;
  if (b < NNODES / 32) {
    gin_block<78, 96, false, false>(b, x_lig, nullptr, Oh0, row_ptr, csr_src,
                                    ws, b1, ws + 24576, b2,
                                    nullptr, nullptr, nullptr, nullptr,
                                    bn_sum, bn_sq, buf);
  } else if (b < NNODES / 32 + (NGRAPHS / 16) * 5) {
    const int q = b - NNODES / 32;
    a2h_block(q & 127, q >> 7, a2h, a1W, a1b, XA, buf);
  } else {
    conv_block(b - (NNODES / 32 + (NGRAPHS / 16) * 5), pseq, convk, convb, XP32, buf);
  }
}

// ---------------- gin wrapper (layers 1,2) + a2h tail ----------------
__global__ __launch_bounds__(256, 4) void gin_kernel(
    const unsigned short* __restrict__ OhIn, unsigned short* __restrict__ OhOut,
    const int* __restrict__ row_ptr, const int* __restrict__ csr_src,
    const short* __restrict__ w1s, const float* __restrict__ b1,
    const short* __restrict__ w2s, const float* __restrict__ b2,
    const float* __restrict__ psum, const float* __restrict__ psq,
    const float* __restrict__ bg, const float* __restrict__ bb2,
    float* __restrict__ bn_sum, float* __restrict__ bn_sq,
    const float* __restrict__ a2h, const float* __restrict__ a1W,
    const float* __restrict__ a1b, float* __restrict__ XA, int sp_base) {
  __shared__ __align__(16) float buf[32 * STRK];
  const int b = blockIdx.x;
  if (b < NNODES / 32) {
    gin_block<128, 128, true, true>(b, nullptr, OhIn, OhOut, row_ptr, csr_src,
                                    w1s, b1, w2s, b2,
                                    psum, psq, bg, bb2,
                                    bn_sum, bn_sq, buf);
  } else {
    const int q = b - NNODES / 32;
    a2h_block(q & 127, sp_base + (q >> 7), a2h, a1W, a1b, XA, buf);
  }
}

// ---------------- mega-head ----------------
__global__ __launch_bounds__(256) void head_kernel(
    const unsigned short* __restrict__ Oh, const int* __restrict__ gp,
    const float* __restrict__ psum, const float* __restrict__ psq,
    const float* __restrict__ bg, const float* __restrict__ bb2,
    const float* __restrict__ XP32, const float* __restrict__ XA,
    const float* __restrict__ ligW, const float* __restrict__ ligb,
    const float* __restrict__ protW, const float* __restrict__ protb,
    const float* __restrict__ a2W, const float* __restrict__ a2b,
    const float* __restrict__ c1W, const float* __restrict__ c1b,
    const float* __restrict__ c2W, const float* __restrict__ c2b,
    const float* __restrict__ oW, const float* __restrict__ ob,
    float* __restrict__ out) {
  __shared__ float Ps[4][128];
  __shared__ float XAs[4][128];
  __shared__ float XPs[4][32];
  __shared__ float XCs[4][384];
  __shared__ float XC2s[4][256];
  __shared__ float XC3s[4][128];
  const int t = threadIdx.x;
  const int g0 = blockIdx.x * 4;

  // phase A: pool (inline BN of layer 2, f16 O) + stage XA(relu) / XP
  {
    const int sub = t >> 6, lane = t & 63;
    const int g = g0 + sub;
    const int f0 = lane, f1 = lane + 64;
    float mu0 = psum[f0] * (1.0f / NNODES);
    float va0 = fmaxf(psq[f0] * (1.0f / NNODES) - mu0 * mu0, 0.0f);
    float sc0 = bg[f0] / sqrtf(va0 + 1e-5f);
    float sh0 = bb2[f0] - mu0 * sc0;
    float mu1 = psum[f1] * (1.0f / NNODES);
    float va1 = fmaxf(psq[f1] * (1.0f / NNODES) - mu1 * mu1, 0.0f);
    float sc1 = bg[f1] / sqrtf(va1 + 1e-5f);
    float sh1 = bb2[f1] - mu1 * sc1;
    const int n0 = gp[g], n1 = gp[g + 1];
    float a0 = 0.f, a1 = 0.f;
    for (int n = n0; n < n1; ++n) {
      a0 += relu_f(fmaf(h2f(Oh[(size_t)n * HIDDEN + f0]), sc0, sh0));
      a1 += relu_f(fmaf(h2f(Oh[(size_t)n * HIDDEN + f1]), sc1, sh1));
    }
    Ps[sub][f0] = a0;
    Ps[sub][f1] = a1;
    for (int i = t; i < 512; i += 256) XAs[i >> 7][i & 127] = relu_f(XA[g0 * 128 + i]);
    for (int i = t; i < 128; i += 256) XPs[i >> 5][i & 31] = XP32[g0 * 32 + i];
  }
  __syncthreads();

  // phase B: lig / prot / a2 -> XCs
  {
    const int j = t & 127, pr = t >> 7;
    const int s0 = pr * 2, s1 = pr * 2 + 1;
    float L0 = ligb[j], L1 = L0;
    float A0 = a2b[j], A1 = A0;
    for (int k = 0; k < 128; ++k) {
      const float wl = ligW[k * 128 + j];
      const float wa = a2W[k * 128 + j];
      L0 = fmaf(Ps[s0][k], wl, L0); L1 = fmaf(Ps[s1][k], wl, L1);
      A0 = fmaf(XAs[s0][k], wa, A0); A1 = fmaf(XAs[s1][k], wa, A1);
    }
    float P0 = protb[j], P1 = P0;
    for (int k = 0; k < 32; ++k) {
      const float wp = protW[k * 128 + j];
      P0 = fmaf(XPs[s0][k], wp, P0); P1 = fmaf(XPs[s1][k], wp, P1);
    }
    XCs[s0][j] = relu_f(L0);        XCs[s1][j] = relu_f(L1);
    XCs[s0][128 + j] = relu_f(P0);  XCs[s1][128 + j] = relu_f(P1);
    XCs[s0][256 + j] = relu_f(A0);  XCs[s1][256 + j] = relu_f(A1);
  }
  __syncthreads();

  // phase C: c1 (384 -> 256)
  {
    const int j = t;
    float a[4];
    const float bv = c1b[j];
    for (int s = 0; s < 4; ++s) a[s] = bv;
    for (int k = 0; k < 384; ++k) {
      const float w = c1W[k * 256 + j];
      for (int s = 0; s < 4; ++s) a[s] = fmaf(XCs[s][k], w, a[s]);
    }
    for (int s = 0; s < 4; ++s) XC2s[s][j] = relu_f(a[s]);
  }
  __syncthreads();

  // phase D: c2 (256 -> 128)
  {
    const int j = t & 127, pr = t >> 7;
    const int s0 = pr * 2, s1 = pr * 2 + 1;
    float a0 = c2b[j], a1 = a0;
    for (int k = 0; k < 256; ++k) {
      const float w = c2W[k * 128 + j];
      a0 = fmaf(XC2s[s0][k], w, a0);
      a1 = fmaf(XC2s[s1][k], w, a1);
    }
    XC3s[s0][j] = relu_f(a0);
    XC3s[s1][j] = relu_f(a1);
  }
  __syncthreads();

  // phase E: out (128 -> 1)
  {
    const int w = t >> 6, lane = t & 63;
    float p = XC3s[w][lane] * oW[lane] + XC3s[w][lane + 64] * oW[lane + 64];
    for (int off = 32; off >= 1; off >>= 1) p += __shfl_down(p, off);
    if (lane == 0) out[g0 + w] = p + ob[0];
  }
}

extern "C" void kernel_launch(void* const* d_in, const int* in_sizes, int n_in,
                              void* d_out, int out_size, void* d_ws, size_t ws_size,
                              hipStream_t stream) {
  const float* x_lig = (const float*)d_in[0];
  const float* pseq  = (const float*)d_in[1];
  const float* a2h   = (const float*)d_in[2];
  const int*   ei    = (const int*)d_in[3];
  const int*   batch = (const int*)d_in[4];
  const float* ginW1[3] = {(const float*)d_in[5],  (const float*)d_in[11], (const float*)d_in[17]};
  const float* ginb1[3] = {(const float*)d_in[6],  (const float*)d_in[12], (const float*)d_in[18]};
  const float* ginW2[3] = {(const float*)d_in[7],  (const float*)d_in[13], (const float*)d_in[19]};
  const float* ginb2[3] = {(const float*)d_in[8],  (const float*)d_in[14], (const float*)d_in[20]};
  const float* bng[3]   = {(const float*)d_in[9],  (const float*)d_in[15], (const float*)d_in[21]};
  const float* bnb[3]   = {(const float*)d_in[10], (const float*)d_in[16], (const float*)d_in[22]};
  const float* ligW  = (const float*)d_in[23]; const float* ligb  = (const float*)d_in[24];
  const float* convk = (const float*)d_in[25]; const float* convb = (const float*)d_in[26];
  const float* protW = (const float*)d_in[27]; const float* protb = (const float*)d_in[28];
  const float* a1W   = (const float*)d_in[29]; const float* a1b   = (const float*)d_in[30];
  const float* a2W   = (const float*)d_in[31]; const float* a2b   = (const float*)d_in[32];
  const float* c1W   = (const float*)d_in[33]; const float* c1b   = (const float*)d_in[34];
  const float* c2W   = (const float*)d_in[35]; const float* c2b   = (const float*)d_in[36];
  const float* oW    = (const float*)d_in[37]; const float* ob    = (const float*)d_in[38];

  char* base = (char*)d_ws;
  size_t off = 0;
  auto alloc = [&](size_t bytes) -> char* {
    char* p = base + off;
    off = (off + bytes + 511) & ~size_t(511);
    return p;
  };
  int*   counts  = (int*)alloc(NNODES * 4);
  int*   gcounts = (int*)alloc(NGRAPHS * 4);
  float* bn_sum  = (float*)alloc(3 * 128 * 4);
  float* bn_sq   = (float*)alloc(3 * 128 * 4);
  float* XA      = (float*)alloc((size_t)NGRAPHS * HIDDEN * 4);
  const size_t zero_bytes = off;
  short* wsplit   = (short*)alloc(188416 * 2);
  int*   row_ptr  = (int*)alloc((NNODES + 1) * 4);
  int*   nxt      = (int*)alloc(NNODES * 4);
  int*   gptr     = (int*)alloc((NGRAPHS + 1) * 4);
  int*   bsumsA   = (int*)alloc(401 * 4);
  int*   bsumsB   = (int*)alloc(9 * 4);
  int*   csr_src  = (int*)alloc(NEDGES * 4);
  float* XP32     = (float*)alloc(NGRAPHS * 32 * 4);
  unsigned short* Oh0 = (unsigned short*)alloc((size_t)NNODES * 128 * 2);
  unsigned short* Oh1 = (unsigned short*)alloc((size_t)NNODES * 128 * 2);
  (void)ws_size; (void)in_sizes; (void)n_in; (void)out_size;

  hipMemsetAsync(d_ws, 0, zero_bytes, stream);

  prep_kernel<<<NEDGES / 256 + NNODES / 256 + 736, 256, 0, stream>>>(
      ei, batch, counts, gcounts, ginW1[0], ginW2[0], ginW1[1], ginW2[1],
      ginW1[2], ginW2[2], wsplit);
  scan_block2_kernel<<<NNODES / 256 + NGRAPHS / 256, 256, 0, stream>>>(
      counts, row_ptr, bsumsA, gcounts, gptr, bsumsB);
  scan_top2_kernel<<<2, 1024, 0, stream>>>(bsumsA, bsumsB);
  scan_add2_kernel<<<NNODES / 256 + NGRAPHS / 256, 256, 0, stream>>>(
      row_ptr, bsumsA, nxt, gptr, bsumsB);
  scatter_kernel<<<(NEDGES + 255) / 256, 256, 0, stream>>>(ei, nxt, csr_src);

  // layer 0 (+ a2h sp 0-4 + conv)
  fat0_kernel<<<NNODES / 32 + (NGRAPHS / 16) * 5 + NGRAPHS, 256, 0, stream>>>(
      x_lig, Oh0, row_ptr, csr_src, wsplit, ginb1[0], ginb2[0],
      bn_sum, bn_sq, a2h, a1W, a1b, XA, pseq, convk, convb, XP32);

  // layer 1: gather f16 Oh0 (BN0 on consume) -> Oh1 (+ a2h sp 5-9)
  gin_kernel<<<NNODES / 32 + (NGRAPHS / 16) * 5, 256, 0, stream>>>(
      Oh0, Oh1, row_ptr, csr_src,
      wsplit + 57344, ginb1[1], wsplit + 90112, ginb2[1],
      bn_sum, bn_sq, bng[0], bnb[0],
      bn_sum + 128, bn_sq + 128, a2h, a1W, a1b, XA, 5);

  // layer 2: gather f16 Oh1 (BN1 on consume) -> Oh0 (+ a2h sp 10-14)
  gin_kernel<<<NNODES / 32 + (NGRAPHS / 16) * 5, 256, 0, stream>>>(
      Oh1, Oh0, row_ptr, csr_src,
      wsplit + 122880, ginb1[2], wsplit + 155648, ginb2[2],
      bn_sum + 128, bn_sq + 128, bng[1], bnb[1],
      bn_sum + 256, bn_sq + 256, a2h, a1W, a1b, XA, 10);

  head_kernel<<<NGRAPHS / 4, 256, 0, stream>>>(Oh0, gptr,
      bn_sum + 256, bn_sq + 256, bng[2], bnb[2], XP32, XA,
      ligW, ligb, protW, protb, a2W, a2b, c1W, c1b, c2W, c2b, oW, ob, (float*)d_out);
}